// Round 3
// baseline (527.095 us; speedup 1.0000x reference)
//
#include <hip/hip_runtime.h>
#include <hip/hip_bf16.h>
#include <math.h>

#define T_SEQ 2048
#define DM 1024
#define NH 16
#define DH 64
#define CHUNK 64
#define NCHUNK (T_SEQ / CHUNK)   // 32

typedef __hip_bfloat16 bf16;
typedef __attribute__((ext_vector_type(8))) short short8;
typedef __attribute__((ext_vector_type(4))) short short4v;
typedef __attribute__((ext_vector_type(4))) float f32x4;

static __device__ __forceinline__ short f2b_bits(float f) {
  bf16 t = __float2bfloat16(f);
  short s;
  __builtin_memcpy(&s, &t, 2);
  return s;
}

// async global->LDS, 16B per lane; LDS dest must be wave-uniform base + lane*16
static __device__ __forceinline__ void gload16(const void* g, void* l) {
  __builtin_amdgcn_global_load_lds((const __attribute__((address_space(1))) void*)g,
                                   (__attribute__((address_space(3))) void*)l, 16, 0, 0);
}

// ---------------------------------------------------------------------------
// fp32 -> bf16 conversion (weights), float4 vectorized. n must be /4.
// ---------------------------------------------------------------------------
__global__ __launch_bounds__(256) void f2b_kernel(const float* __restrict__ in,
                                                  bf16* __restrict__ out, int n4) {
  int i = blockIdx.x * 256 + threadIdx.x;
  if (i >= n4) return;
  float4 v = ((const float4*)in)[i];
  short4v s;
  s.x = f2b_bits(v.x); s.y = f2b_bits(v.y); s.z = f2b_bits(v.z); s.w = f2b_bits(v.w);
  *(short4v*)&out[i * 4] = s;
}

// ---------------------------------------------------------------------------
// LayerNorm (fp32 in) -> xn bf16, plus bf16 copy of raw x for gate GEMM.
// ---------------------------------------------------------------------------
__global__ __launch_bounds__(256) void ln_kernel(const float* __restrict__ x,
                                                 const float* __restrict__ g,
                                                 const float* __restrict__ b,
                                                 bf16* __restrict__ xn,
                                                 bf16* __restrict__ xbf) {
  const int row = blockIdx.x;
  const float* xr = x + (size_t)row * DM;
  float vals[4];
  float s = 0.f, s2 = 0.f;
#pragma unroll
  for (int i = 0; i < 4; i++) {
    float v = xr[threadIdx.x + i * 256];
    vals[i] = v;
    s += v;
    s2 += v * v;
  }
#pragma unroll
  for (int m = 1; m < 64; m <<= 1) {
    s += __shfl_xor(s, m, 64);
    s2 += __shfl_xor(s2, m, 64);
  }
  __shared__ float red[8];
  const int wid = threadIdx.x >> 6;
  if ((threadIdx.x & 63) == 0) {
    red[wid] = s;
    red[4 + wid] = s2;
  }
  __syncthreads();
  s = red[0] + red[1] + red[2] + red[3];
  s2 = red[4] + red[5] + red[6] + red[7];
  const float mean = s * (1.f / DM);
  const float var = s2 * (1.f / DM) - mean * mean;
  const float rstd = rsqrtf(var + 1e-5f);
#pragma unroll
  for (int i = 0; i < 4; i++) {
    int idx = threadIdx.x + i * 256;
    float v = (vals[i] - mean) * rstd * g[idx] + b[idx];
    xn[(size_t)row * DM + idx] = __float2bfloat16(v);
    xbf[(size_t)row * DM + idx] = __float2bfloat16(vals[i]);
  }
}

// ---------------------------------------------------------------------------
// GEMM C = A(MxK,bf16) * W(NxK,bf16)^T + bias(fp32). m97 structure:
// global_load_lds width=16 staging, unpadded 32-short LDS rows.
// ---------------------------------------------------------------------------
template <int MODE>
__global__ __launch_bounds__(256) void gemm_bt(
    const bf16* __restrict__ A, const bf16* __restrict__ W,
    const float* __restrict__ bias,
    float* __restrict__ gate_sig, const float* __restrict__ inv_den,
    float* __restrict__ Qo, float* __restrict__ Ko, float* __restrict__ Vo,
    float* __restrict__ Cout) {
  constexpr int K = 1024;
  __shared__ __align__(16) short As[128 * 32];
  __shared__ __align__(16) short Bs[128 * 32];

  const int tid = threadIdx.x;
  const int wid = tid >> 6, lane = tid & 63;
  const int wm = wid >> 1, wn = wid & 1;
  const int lm = lane & 15, quad = lane >> 4;

  const int m0 = blockIdx.x * 128;
  const int n0 = blockIdx.y * 128;

  const short* Ag = (const short*)A;
  const short* Wg = (const short*)W;

  f32x4 zero = {0.f, 0.f, 0.f, 0.f};
  f32x4 acc[4][4];
#pragma unroll
  for (int i = 0; i < 4; i++)
#pragma unroll
    for (int j = 0; j < 4; j++) acc[i][j] = zero;

  for (int kb = 0; kb < K; kb += 32) {
    __syncthreads();
#pragma unroll
    for (int it = 0; it < 2; it++) {
      const int idx = it * 256 + tid;
      const int row = idx >> 2, seg = (idx & 3) * 8;
      gload16(&Ag[(size_t)(m0 + row) * K + kb + seg], &As[(it * 256 + wid * 64) * 8]);
      gload16(&Wg[(size_t)(n0 + row) * K + kb + seg], &Bs[(it * 256 + wid * 64) * 8]);
    }
    __syncthreads();
    short8 afr[4], bfr[4];
#pragma unroll
    for (int i = 0; i < 4; i++) {
      afr[i] = *(const short8*)&As[(wm * 64 + i * 16 + lm) * 32 + quad * 8];
      bfr[i] = *(const short8*)&Bs[(wn * 64 + i * 16 + lm) * 32 + quad * 8];
    }
#pragma unroll
    for (int i = 0; i < 4; i++)
#pragma unroll
      for (int j = 0; j < 4; j++)
        acc[i][j] = __builtin_amdgcn_mfma_f32_16x16x32_bf16(afr[i], bfr[j], acc[i][j], 0, 0, 0);
  }

  // epilogue: C/D layout col = lane&15, row = quad*4 + r
#pragma unroll
  for (int i = 0; i < 4; i++) {
    const int rbase = m0 + wm * 64 + i * 16 + quad * 4;
#pragma unroll
    for (int j = 0; j < 4; j++) {
      const int col = n0 + wn * 64 + j * 16 + lm;
      const float bval = bias[col];
#pragma unroll
      for (int r = 0; r < 4; r++) {
        const int row = rbase + r;
        float v = acc[i][j][r] + bval;
        if (MODE == 0) {
          gate_sig[(size_t)row * DM + col] = 1.f / (1.f + __expf(-v));
        } else if (MODE == 1) {
          if (col < DM) {
            const int d = col;
            float gn = gate_sig[(size_t)row * DM + d] * inv_den[row];
            float q = v * gn;
            q = q > 0.f ? q + 1.f : __expf(q);
            Qo[((size_t)(d >> 6) * T_SEQ + row) * DH + (d & 63)] = q;
          } else if (col < 2 * DM) {
            const int d = col - DM;
            float gn = gate_sig[(size_t)row * DM + d] * inv_den[row];
            float kk = v * gn;
            kk = kk > 0.f ? kk + 1.f : __expf(kk);
            Ko[((size_t)(d >> 6) * T_SEQ + row) * DH + (d & 63)] = kk;
          } else {
            const int d = col - 2 * DM;
            Vo[((size_t)(d >> 6) * T_SEQ + row) * DH + (d & 63)] = v;
          }
        } else {
          Cout[(size_t)row * DM + col] = v;
        }
      }
    }
  }
}

// ---------------------------------------------------------------------------
// Gate row mean -> inv_den[row] = 1/(mean + EPS_GATE)
// ---------------------------------------------------------------------------
__global__ __launch_bounds__(256) void gate_mean_kernel(const float* __restrict__ gate_sig,
                                                        float* __restrict__ inv_den) {
  const int row = blockIdx.x;
  float s = 0.f;
  for (int i = threadIdx.x; i < DM; i += 256) s += gate_sig[(size_t)row * DM + i];
#pragma unroll
  for (int m = 1; m < 64; m <<= 1) s += __shfl_xor(s, m, 64);
  __shared__ float red[4];
  if ((threadIdx.x & 63) == 0) red[threadIdx.x >> 6] = s;
  __syncthreads();
  if (threadIdx.x == 0) {
    float tot = red[0] + red[1] + red[2] + red[3];
    inv_den[row] = 1.f / (tot * (1.f / DM) + 1e-5f);
  }
}

// ---------------------------------------------------------------------------
// Pass A (matmul form): per (h,c) Skv_c[d][m] = K^T V (64x64, Kdim=64),
// Sk_c[d] = column sums of K. Grid NH*NCHUNK = 512, block 256 (4x4/thread).
// ---------------------------------------------------------------------------
__global__ __launch_bounds__(256, 2) void chunk_sum_mm(const float* __restrict__ Ko,
                                                       const float* __restrict__ Vo,
                                                       float* __restrict__ Skv,
                                                       float* __restrict__ Sk) {
  constexpr int STR = 68;
  __shared__ __align__(16) float Ks2[64 * STR];
  __shared__ __align__(16) float Vs2[64 * STR];
  const int b = blockIdx.x;
  const int h = b >> 5, c = b & 31;
  const int tid = threadIdx.x;
  const int ty = tid >> 4, tx = tid & 15;
  const int d0 = ty * 4, m0 = tx * 4;
  const size_t cb = ((size_t)h * T_SEQ + c * CHUNK) * DH;
  const float* Kg = Ko + cb;
  const float* Vg = Vo + cb;
#pragma unroll
  for (int p = 0; p < 4; p++) {
    int f = p * 256 + tid, row = f >> 4, seg = (f & 15) * 4;
    *(f32x4*)&Ks2[row * STR + seg] = *(const f32x4*)&Kg[row * 64 + seg];
    *(f32x4*)&Vs2[row * STR + seg] = *(const f32x4*)&Vg[row * 64 + seg];
  }
  __syncthreads();
  float acc[4][4] = {};
  for (int s = 0; s < 64; s++) {
    f32x4 kf = *(const f32x4*)&Ks2[s * STR + d0];
    f32x4 vf = *(const f32x4*)&Vs2[s * STR + m0];
#pragma unroll
    for (int i = 0; i < 4; i++)
#pragma unroll
      for (int j = 0; j < 4; j++) acc[i][j] += kf[i] * vf[j];
  }
  float* outp = Skv + (size_t)b * 4096;
#pragma unroll
  for (int i = 0; i < 4; i++) {
    f32x4 o = {acc[i][0], acc[i][1], acc[i][2], acc[i][3]};
    *(f32x4*)&outp[(d0 + i) * 64 + m0] = o;
  }
  if (tid < 64) {
    float ss = 0.f;
    for (int s = 0; s < 64; s++) ss += Ks2[s * STR + tid];
    Sk[b * 64 + tid] = ss;
  }
}

// ---------------------------------------------------------------------------
// Pass B: exclusive prefix over chunks, one thread per (h,e) chain;
// load all 32 into registers (independent loads), scan, store back.
// Grid 260: blocks 0..255 -> Skv chains, 256..259 -> Sk chains.
// ---------------------------------------------------------------------------
__global__ __launch_bounds__(256) void scan_excl(float* __restrict__ Skv,
                                                 float* __restrict__ Sk) {
  const int bid = blockIdx.x, tid = threadIdx.x;
  if (bid < 256) {
    const int id = bid * 256 + tid;
    const int h = id >> 12, e = id & 4095;
    float* base = Skv + (size_t)h * NCHUNK * 4096 + e;
    float v[NCHUNK];
#pragma unroll
    for (int c = 0; c < NCHUNK; c++) v[c] = base[(size_t)c * 4096];
    float run = 0.f;
#pragma unroll
    for (int c = 0; c < NCHUNK; c++) {
      float t = v[c];
      base[(size_t)c * 4096] = run;
      run += t;
    }
  } else {
    const int id = (bid - 256) * 256 + tid;
    const int h = id >> 6, e = id & 63;
    float* base = Sk + (size_t)h * NCHUNK * 64 + e;
    float v[NCHUNK];
#pragma unroll
    for (int c = 0; c < NCHUNK; c++) v[c] = base[c * 64];
    float run = 0.f;
#pragma unroll
    for (int c = 0; c < NCHUNK; c++) {
      float t = v[c];
      base[c * 64] = run;
      run += t;
    }
  }
}

// ---------------------------------------------------------------------------
// Pass C (matmul form): per (h,c):
//   S = Q K^T (causal masked), O = S V + Q P_prefix, den = rowsum(S) + q.Skp.
// No recurrence, no per-step barriers. Grid 512, block 256.
// LDS: Qs (reused as S after B2), KT (K transposed), Vs, partial-den arrays.
// ---------------------------------------------------------------------------
__global__ __launch_bounds__(256, 2) void attn_mm(const float* __restrict__ Qo,
                                                  const float* __restrict__ Ko,
                                                  const float* __restrict__ Vo,
                                                  const float* __restrict__ Skv,
                                                  const float* __restrict__ Sk,
                                                  bf16* __restrict__ O) {
  constexpr int STR = 68;
  __shared__ __align__(16) float Qs[64 * STR];   // becomes S after B2
  __shared__ __align__(16) float KT[64 * STR];
  __shared__ __align__(16) float Vs[64 * STR];
  __shared__ float denp[64 * 16];
  __shared__ float skp[64];
  __shared__ float den[64];
  const int b = blockIdx.x;
  const int h = b >> 5, c = b & 31;
  const int tid = threadIdx.x;
  const int ty = tid >> 4, tx = tid & 15;
  const int r0 = ty * 4, c0 = tx * 4, m0 = tx * 4;
  const size_t cb = ((size_t)h * T_SEQ + c * CHUNK) * DH;
  const float* Qg = Qo + cb;
  const float* Kg = Ko + cb;
  const float* Vg = Vo + cb;
  const float* Pg = Skv + (size_t)b * 4096;

  // stage Q, V natural; K transposed
#pragma unroll
  for (int p = 0; p < 4; p++) {
    int f = p * 256 + tid, row = f >> 4, seg = (f & 15) * 4;
    *(f32x4*)&Qs[row * STR + seg] = *(const f32x4*)&Qg[row * 64 + seg];
    *(f32x4*)&Vs[row * STR + seg] = *(const f32x4*)&Vg[row * 64 + seg];
  }
  {
    const int s = tid & 63, w = tid >> 6;
#pragma unroll
    for (int p = 0; p < 4; p++) {
      const int d0 = w * 16 + p * 4;
      f32x4 kf = *(const f32x4*)&Kg[s * 64 + d0];
      KT[(d0 + 0) * STR + s] = kf[0];
      KT[(d0 + 1) * STR + s] = kf[1];
      KT[(d0 + 2) * STR + s] = kf[2];
      KT[(d0 + 3) * STR + s] = kf[3];
    }
  }
  if (tid < 64) skp[tid] = Sk[b * 64 + tid];
  __syncthreads();  // B1

  // den init: q . Sk_prefix + EPS_DEN
  if (tid < 64) {
    float s = 1e-5f;
    for (int d = 0; d < 64; d++) s += Qs[tid * STR + d] * skp[d];
    den[tid] = s;
  }

  // O partial: Q . P  (P read straight from global/L2)
  float accO[4][4] = {};
  for (int d0 = 0; d0 < 64; d0 += 4) {
    f32x4 qf[4], pf[4];
#pragma unroll
    for (int i = 0; i < 4; i++) qf[i] = *(const f32x4*)&Qs[(r0 + i) * STR + d0];
#pragma unroll
    for (int dd = 0; dd < 4; dd++) pf[dd] = *(const f32x4*)&Pg[(d0 + dd) * 64 + m0];
#pragma unroll
    for (int i = 0; i < 4; i++)
#pragma unroll
      for (int j = 0; j < 4; j++)
        accO[i][j] += qf[i][0] * pf[0][j] + qf[i][1] * pf[1][j] +
                      qf[i][2] * pf[2][j] + qf[i][3] * pf[3][j];
  }

  // S = Q K^T
  float accS[4][4] = {};
  for (int d0 = 0; d0 < 64; d0 += 4) {
    f32x4 qf[4], kf[4];
#pragma unroll
    for (int i = 0; i < 4; i++) qf[i] = *(const f32x4*)&Qs[(r0 + i) * STR + d0];
#pragma unroll
    for (int dd = 0; dd < 4; dd++) kf[dd] = *(const f32x4*)&KT[(d0 + dd) * STR + c0];
#pragma unroll
    for (int i = 0; i < 4; i++)
#pragma unroll
      for (int j = 0; j < 4; j++)
        accS[i][j] += qf[i][0] * kf[0][j] + qf[i][1] * kf[1][j] +
                      qf[i][2] * kf[2][j] + qf[i][3] * kf[3][j];
  }
  // causal mask (inclusive) + row-sum partials
  float dp[4];
#pragma unroll
  for (int i = 0; i < 4; i++) {
    dp[i] = 0.f;
#pragma unroll
    for (int j = 0; j < 4; j++) {
      float v = (c0 + j) <= (r0 + i) ? accS[i][j] : 0.f;
      accS[i][j] = v;
      dp[i] += v;
    }
  }
  __syncthreads();  // B2: all Qs/KT reads complete -> safe to overwrite Qs with S
#pragma unroll
  for (int i = 0; i < 4; i++) {
    f32x4 sv = {accS[i][0], accS[i][1], accS[i][2], accS[i][3]};
    *(f32x4*)&Qs[(r0 + i) * STR + c0] = sv;
    denp[(r0 + i) * 16 + tx] = dp[i];
  }
  __syncthreads();  // B3
  if (tid < 64) {
    float s = den[tid];
#pragma unroll
    for (int t = 0; t < 16; t++) s += denp[tid * 16 + t];
    den[tid] = s;
  }
  __syncthreads();  // B4

  // O += S . V
  for (int c4 = 0; c4 < 64; c4 += 4) {
    f32x4 sf[4], vf[4];
#pragma unroll
    for (int i = 0; i < 4; i++) sf[i] = *(const f32x4*)&Qs[(r0 + i) * STR + c4];
#pragma unroll
    for (int cc = 0; cc < 4; cc++) vf[cc] = *(const f32x4*)&Vs[(c4 + cc) * STR + m0];
#pragma unroll
    for (int i = 0; i < 4; i++)
#pragma unroll
      for (int j = 0; j < 4; j++)
        accO[i][j] += sf[i][0] * vf[0][j] + sf[i][1] * vf[1][j] +
                      sf[i][2] * vf[2][j] + sf[i][3] * vf[3][j];
  }

  // divide + store bf16 [T][DM]
#pragma unroll
  for (int i = 0; i < 4; i++) {
    const float inv = 1.f / den[r0 + i];
    short4v ov;
#pragma unroll
    for (int j = 0; j < 4; j++) ov[j] = f2b_bits(accO[i][j] * inv);
    *(short4v*)&O[(size_t)(c * CHUNK + r0 + i) * DM + h * 64 + m0] = ov;
  }
}

// ---------------------------------------------------------------------------
extern "C" void kernel_launch(void* const* d_in, const int* in_sizes, int n_in,
                              void* d_out, int out_size, void* d_ws, size_t ws_size,
                              hipStream_t stream) {
  (void)in_sizes; (void)n_in; (void)out_size; (void)ws_size;
  const float* x      = (const float*)d_in[0];
  const float* ln_g   = (const float*)d_in[1];
  const float* ln_b   = (const float*)d_in[2];
  const float* qkv_w  = (const float*)d_in[3];
  const float* qkv_b  = (const float*)d_in[4];
  const float* gate_w = (const float*)d_in[5];
  const float* gate_b = (const float*)d_in[6];
  const float* proj_w = (const float*)d_in[7];
  const float* proj_b = (const float*)d_in[8];
  float* out = (float*)d_out;

  char* ws = (char*)d_ws;
  size_t off = 0;
  auto alloc = [&](size_t bytes) {
    void* p = ws + off;
    off += (bytes + 255) & ~(size_t)255;
    return p;
  };
  bf16*  xn       = (bf16*)alloc((size_t)T_SEQ * DM * 2);
  bf16*  xbf      = (bf16*)alloc((size_t)T_SEQ * DM * 2);
  bf16*  wqkv     = (bf16*)alloc((size_t)3 * DM * DM * 2);
  bf16*  wgate    = (bf16*)alloc((size_t)DM * DM * 2);
  bf16*  wproj    = (bf16*)alloc((size_t)DM * DM * 2);
  float* gate_sig = (float*)alloc((size_t)T_SEQ * DM * 4);
  float* inv_den  = (float*)alloc((size_t)T_SEQ * 4);
  float* Qo       = (float*)alloc((size_t)T_SEQ * DM * 4);
  float* Ko       = (float*)alloc((size_t)T_SEQ * DM * 4);
  float* Vo       = (float*)alloc((size_t)T_SEQ * DM * 4);
  bf16*  Obuf     = (bf16*)alloc((size_t)T_SEQ * DM * 2);
  float* Skv      = (float*)alloc((size_t)NH * NCHUNK * 4096 * 4);
  float* Sk       = (float*)alloc((size_t)NH * NCHUNK * 64 * 4);

  const int n4_qkv = 3 * DM * DM / 4;
  const int n4_sq  = DM * DM / 4;
  f2b_kernel<<<(n4_qkv + 255) / 256, 256, 0, stream>>>(qkv_w, wqkv, n4_qkv);
  f2b_kernel<<<(n4_sq + 255) / 256, 256, 0, stream>>>(gate_w, wgate, n4_sq);
  f2b_kernel<<<(n4_sq + 255) / 256, 256, 0, stream>>>(proj_w, wproj, n4_sq);

  ln_kernel<<<T_SEQ, 256, 0, stream>>>(x, ln_g, ln_b, xn, xbf);
  gemm_bt<0><<<dim3(16, 8), 256, 0, stream>>>(xbf, wgate, gate_b, gate_sig, nullptr,
                                              nullptr, nullptr, nullptr, nullptr);
  gate_mean_kernel<<<T_SEQ, 256, 0, stream>>>(gate_sig, inv_den);
  gemm_bt<1><<<dim3(16, 24), 256, 0, stream>>>(xn, wqkv, qkv_b, gate_sig, inv_den,
                                               Qo, Ko, Vo, nullptr);
  chunk_sum_mm<<<NH * NCHUNK, 256, 0, stream>>>(Ko, Vo, Skv, Sk);
  scan_excl<<<260, 256, 0, stream>>>(Skv, Sk);
  attn_mm<<<NH * NCHUNK, 256, 0, stream>>>(Qo, Ko, Vo, Skv, Sk, Obuf);
  gemm_bt<2><<<dim3(16, 8), 256, 0, stream>>>(Obuf, wproj, proj_b, nullptr, nullptr,
                                              nullptr, nullptr, nullptr, out);
}

// Round 4
// 208.103 us; speedup vs baseline: 2.5329x; 2.5329x over previous
//
#include <hip/hip_runtime.h>
#include <hip/hip_bf16.h>
#include <math.h>

#define T_SEQ 2048
#define DM 1024
#define NH 16
#define DH 64
#define CHUNK 64
#define NCHUNK (T_SEQ / CHUNK)   // 32

typedef __hip_bfloat16 bf16;
typedef __attribute__((ext_vector_type(8))) short short8;
typedef __attribute__((ext_vector_type(4))) short short4v;
typedef __attribute__((ext_vector_type(4))) float f32x4;

static __device__ __forceinline__ short f2b_bits(float f) {
  bf16 t = __float2bfloat16(f);
  short s;
  __builtin_memcpy(&s, &t, 2);
  return s;
}

// async global->LDS, 16B per lane; LDS dest must be wave-uniform base + lane*16
static __device__ __forceinline__ void gload16(const void* g, void* l) {
  __builtin_amdgcn_global_load_lds((const __attribute__((address_space(1))) void*)g,
                                   (__attribute__((address_space(3))) void*)l, 16, 0, 0);
}

// ---------------------------------------------------------------------------
// fp32 -> bf16 conversion (weights), float4 vectorized. n must be /4.
// ---------------------------------------------------------------------------
__global__ __launch_bounds__(256) void f2b_kernel(const float* __restrict__ in,
                                                  bf16* __restrict__ out, int n4) {
  int i = blockIdx.x * 256 + threadIdx.x;
  if (i >= n4) return;
  float4 v = ((const float4*)in)[i];
  short4v s;
  s.x = f2b_bits(v.x); s.y = f2b_bits(v.y); s.z = f2b_bits(v.z); s.w = f2b_bits(v.w);
  *(short4v*)&out[i * 4] = s;
}

// ---------------------------------------------------------------------------
// LayerNorm (fp32 in) -> xn bf16, plus bf16 copy of raw x for gate GEMM.
// ---------------------------------------------------------------------------
__global__ __launch_bounds__(256) void ln_kernel(const float* __restrict__ x,
                                                 const float* __restrict__ g,
                                                 const float* __restrict__ b,
                                                 bf16* __restrict__ xn,
                                                 bf16* __restrict__ xbf) {
  const int row = blockIdx.x;
  const float* xr = x + (size_t)row * DM;
  float vals[4];
  float s = 0.f, s2 = 0.f;
#pragma unroll
  for (int i = 0; i < 4; i++) {
    float v = xr[threadIdx.x + i * 256];
    vals[i] = v;
    s += v;
    s2 += v * v;
  }
#pragma unroll
  for (int m = 1; m < 64; m <<= 1) {
    s += __shfl_xor(s, m, 64);
    s2 += __shfl_xor(s2, m, 64);
  }
  __shared__ float red[8];
  const int wid = threadIdx.x >> 6;
  if ((threadIdx.x & 63) == 0) {
    red[wid] = s;
    red[4 + wid] = s2;
  }
  __syncthreads();
  s = red[0] + red[1] + red[2] + red[3];
  s2 = red[4] + red[5] + red[6] + red[7];
  const float mean = s * (1.f / DM);
  const float var = s2 * (1.f / DM) - mean * mean;
  const float rstd = rsqrtf(var + 1e-5f);
#pragma unroll
  for (int i = 0; i < 4; i++) {
    int idx = threadIdx.x + i * 256;
    float v = (vals[i] - mean) * rstd * g[idx] + b[idx];
    xn[(size_t)row * DM + idx] = __float2bfloat16(v);
    xbf[(size_t)row * DM + idx] = __float2bfloat16(vals[i]);
  }
}

// ---------------------------------------------------------------------------
// GEMM C = A(MxK,bf16) * W(NxK,bf16)^T + bias(fp32). m97 structure:
// global_load_lds width=16 staging, unpadded 32-short LDS rows.
// ---------------------------------------------------------------------------
template <int MODE>
__global__ __launch_bounds__(256) void gemm_bt(
    const bf16* __restrict__ A, const bf16* __restrict__ W,
    const float* __restrict__ bias,
    float* __restrict__ gate_sig, const float* __restrict__ inv_den,
    float* __restrict__ Qo, float* __restrict__ Ko, float* __restrict__ Vo,
    float* __restrict__ Cout) {
  constexpr int K = 1024;
  __shared__ __align__(16) short As[128 * 32];
  __shared__ __align__(16) short Bs[128 * 32];

  const int tid = threadIdx.x;
  const int wid = tid >> 6, lane = tid & 63;
  const int wm = wid >> 1, wn = wid & 1;
  const int lm = lane & 15, quad = lane >> 4;

  const int m0 = blockIdx.x * 128;
  const int n0 = blockIdx.y * 128;

  const short* Ag = (const short*)A;
  const short* Wg = (const short*)W;

  f32x4 zero = {0.f, 0.f, 0.f, 0.f};
  f32x4 acc[4][4];
#pragma unroll
  for (int i = 0; i < 4; i++)
#pragma unroll
    for (int j = 0; j < 4; j++) acc[i][j] = zero;

  for (int kb = 0; kb < K; kb += 32) {
    __syncthreads();
#pragma unroll
    for (int it = 0; it < 2; it++) {
      const int idx = it * 256 + tid;
      const int row = idx >> 2, seg = (idx & 3) * 8;
      gload16(&Ag[(size_t)(m0 + row) * K + kb + seg], &As[(it * 256 + wid * 64) * 8]);
      gload16(&Wg[(size_t)(n0 + row) * K + kb + seg], &Bs[(it * 256 + wid * 64) * 8]);
    }
    __syncthreads();
    short8 afr[4], bfr[4];
#pragma unroll
    for (int i = 0; i < 4; i++) {
      afr[i] = *(const short8*)&As[(wm * 64 + i * 16 + lm) * 32 + quad * 8];
      bfr[i] = *(const short8*)&Bs[(wn * 64 + i * 16 + lm) * 32 + quad * 8];
    }
#pragma unroll
    for (int i = 0; i < 4; i++)
#pragma unroll
      for (int j = 0; j < 4; j++)
        acc[i][j] = __builtin_amdgcn_mfma_f32_16x16x32_bf16(afr[i], bfr[j], acc[i][j], 0, 0, 0);
  }

  // epilogue: C/D layout col = lane&15, row = quad*4 + r
#pragma unroll
  for (int i = 0; i < 4; i++) {
    const int rbase = m0 + wm * 64 + i * 16 + quad * 4;
#pragma unroll
    for (int j = 0; j < 4; j++) {
      const int col = n0 + wn * 64 + j * 16 + lm;
      const float bval = bias[col];
#pragma unroll
      for (int r = 0; r < 4; r++) {
        const int row = rbase + r;
        float v = acc[i][j][r] + bval;
        if (MODE == 0) {
          gate_sig[(size_t)row * DM + col] = 1.f / (1.f + __expf(-v));
        } else if (MODE == 1) {
          if (col < DM) {
            const int d = col;
            float gn = gate_sig[(size_t)row * DM + d] * inv_den[row];
            float q = v * gn;
            q = q > 0.f ? q + 1.f : __expf(q);
            Qo[((size_t)(d >> 6) * T_SEQ + row) * DH + (d & 63)] = q;
          } else if (col < 2 * DM) {
            const int d = col - DM;
            float gn = gate_sig[(size_t)row * DM + d] * inv_den[row];
            float kk = v * gn;
            kk = kk > 0.f ? kk + 1.f : __expf(kk);
            Ko[((size_t)(d >> 6) * T_SEQ + row) * DH + (d & 63)] = kk;
          } else {
            const int d = col - 2 * DM;
            Vo[((size_t)(d >> 6) * T_SEQ + row) * DH + (d & 63)] = v;
          }
        } else {
          Cout[(size_t)row * DM + col] = v;
        }
      }
    }
  }
}

// ---------------------------------------------------------------------------
// Gate row mean -> inv_den[row] = 1/(mean + EPS_GATE)
// ---------------------------------------------------------------------------
__global__ __launch_bounds__(256) void gate_mean_kernel(const float* __restrict__ gate_sig,
                                                        float* __restrict__ inv_den) {
  const int row = blockIdx.x;
  float s = 0.f;
  for (int i = threadIdx.x; i < DM; i += 256) s += gate_sig[(size_t)row * DM + i];
#pragma unroll
  for (int m = 1; m < 64; m <<= 1) s += __shfl_xor(s, m, 64);
  __shared__ float red[4];
  if ((threadIdx.x & 63) == 0) red[threadIdx.x >> 6] = s;
  __syncthreads();
  if (threadIdx.x == 0) {
    float tot = red[0] + red[1] + red[2] + red[3];
    inv_den[row] = 1.f / (tot * (1.f / DM) + 1e-5f);
  }
}

// ---------------------------------------------------------------------------
// Pass A (matmul form): per (h,c) Skv_c[d][m] = K^T V (64x64, Kdim=64),
// Sk_c[d] = column sums of K. Grid NH*NCHUNK = 512, block 256 (4x4/thread).
// ---------------------------------------------------------------------------
__global__ __launch_bounds__(256, 2) void chunk_sum_mm(const float* __restrict__ Ko,
                                                       const float* __restrict__ Vo,
                                                       float* __restrict__ Skv,
                                                       float* __restrict__ Sk) {
  constexpr int STR = 68;
  __shared__ __align__(16) float Ks2[64 * STR];
  __shared__ __align__(16) float Vs2[64 * STR];
  const int b = blockIdx.x;
  const int h = b >> 5, c = b & 31;
  const int tid = threadIdx.x;
  const int ty = tid >> 4, tx = tid & 15;
  const int d0 = ty * 4, m0 = tx * 4;
  const size_t cb = ((size_t)h * T_SEQ + c * CHUNK) * DH;
  const float* Kg = Ko + cb;
  const float* Vg = Vo + cb;
#pragma unroll
  for (int p = 0; p < 4; p++) {
    int f = p * 256 + tid, row = f >> 4, seg = (f & 15) * 4;
    *(f32x4*)&Ks2[row * STR + seg] = *(const f32x4*)&Kg[row * 64 + seg];
    *(f32x4*)&Vs2[row * STR + seg] = *(const f32x4*)&Vg[row * 64 + seg];
  }
  __syncthreads();
  float acc[4][4] = {};
#pragma unroll 4
  for (int s = 0; s < 64; s++) {
    f32x4 kf = *(const f32x4*)&Ks2[s * STR + d0];
    f32x4 vf = *(const f32x4*)&Vs2[s * STR + m0];
#pragma unroll
    for (int i = 0; i < 4; i++)
#pragma unroll
      for (int j = 0; j < 4; j++) acc[i][j] += kf[i] * vf[j];
  }
  float* outp = Skv + (size_t)b * 4096;
#pragma unroll
  for (int i = 0; i < 4; i++) {
    f32x4 o = {acc[i][0], acc[i][1], acc[i][2], acc[i][3]};
    *(f32x4*)&outp[(d0 + i) * 64 + m0] = o;
  }
  if (tid < 64) {
    float ss = 0.f;
#pragma unroll 4
    for (int s = 0; s < 64; s++) ss += Ks2[s * STR + tid];
    Sk[b * 64 + tid] = ss;
  }
}

// ---------------------------------------------------------------------------
// Pass B: exclusive prefix over chunks, one thread per (h,e) chain.
// Grid 260: blocks 0..255 -> Skv chains, 256..259 -> Sk chains.
// ---------------------------------------------------------------------------
__global__ __launch_bounds__(256) void scan_excl(float* __restrict__ Skv,
                                                 float* __restrict__ Sk) {
  const int bid = blockIdx.x, tid = threadIdx.x;
  if (bid < 256) {
    const int id = bid * 256 + tid;
    const int h = id >> 12, e = id & 4095;
    float* base = Skv + (size_t)h * NCHUNK * 4096 + e;
    float v[NCHUNK];
#pragma unroll
    for (int c = 0; c < NCHUNK; c++) v[c] = base[(size_t)c * 4096];
    float run = 0.f;
#pragma unroll
    for (int c = 0; c < NCHUNK; c++) {
      float t = v[c];
      base[(size_t)c * 4096] = run;
      run += t;
    }
  } else {
    const int id = (bid - 256) * 256 + tid;
    const int h = id >> 6, e = id & 63;
    float* base = Sk + (size_t)h * NCHUNK * 64 + e;
    float v[NCHUNK];
#pragma unroll
    for (int c = 0; c < NCHUNK; c++) v[c] = base[c * 64];
    float run = 0.f;
#pragma unroll
    for (int c = 0; c < NCHUNK; c++) {
      float t = v[c];
      base[c * 64] = run;
      run += t;
    }
  }
}

// ---------------------------------------------------------------------------
// Pass C (matmul form): per (h,c):
//   accO = Q.P ; S = Q K^T (causal) ; accO += S.V ; den = q.Skp + rowsum(S).
// ALL in-loop operands come from LDS (no global reads inside unrolled loops:
// R3's global-P reads caused a ~256-VGPR hoist -> scratch spill -> 1 GB HBM).
// P and K share one LDS region (P phase 1, K phase 2; K prefetched to regs).
// ---------------------------------------------------------------------------
__global__ __launch_bounds__(256, 2) void attn_mm(const float* __restrict__ Qo,
                                                  const float* __restrict__ Ko,
                                                  const float* __restrict__ Vo,
                                                  const float* __restrict__ Skv,
                                                  const float* __restrict__ Sk,
                                                  bf16* __restrict__ O) {
  constexpr int STR = 68;
  __shared__ __align__(16) float Qs[64 * STR];   // Q, later S
  __shared__ __align__(16) float Vs[64 * STR];
  __shared__ __align__(16) float KPs[64 * STR];  // P in phase 1, K in phase 2
  __shared__ float denp[64 * 16];
  __shared__ float skp[64];
  __shared__ float den[64];
  const int b = blockIdx.x;
  const int h = b >> 5, c = b & 31;
  const int tid = threadIdx.x;
  const int ty = tid >> 4, tx = tid & 15;
  const int r0 = ty * 4, c0 = tx * 4, m0 = tx * 4;
  const size_t cb = ((size_t)h * T_SEQ + c * CHUNK) * DH;
  const float* Qg = Qo + cb;
  const float* Kg = Ko + cb;
  const float* Vg = Vo + cb;
  const float* Pg = Skv + (size_t)b * 4096;

  // K prefetch into registers (issued first, consumed after phase 1)
  f32x4 kreg[4];
#pragma unroll
  for (int p = 0; p < 4; p++) {
    int f = p * 256 + tid, row = f >> 4, seg = (f & 15) * 4;
    kreg[p] = *(const f32x4*)&Kg[row * 64 + seg];
  }
  // stage Q, V, P (coalesced)
#pragma unroll
  for (int p = 0; p < 4; p++) {
    int f = p * 256 + tid, row = f >> 4, seg = (f & 15) * 4;
    *(f32x4*)&Qs[row * STR + seg] = *(const f32x4*)&Qg[row * 64 + seg];
    *(f32x4*)&Vs[row * STR + seg] = *(const f32x4*)&Vg[row * 64 + seg];
    *(f32x4*)&KPs[row * STR + seg] = *(const f32x4*)&Pg[row * 64 + seg];
  }
  if (tid < 64) skp[tid] = Sk[b * 64 + tid];
  __syncthreads();  // B1

  // den init: q . Sk_prefix + EPS_DEN
  if (tid < 64) {
    float s = 1e-5f;
#pragma unroll 4
    for (int d = 0; d < 64; d++) s += Qs[tid * STR + d] * skp[d];
    den[tid] = s;
  }

  // accO = Q . P   (both LDS)
  float accO[4][4] = {};
#pragma unroll 2
  for (int d0 = 0; d0 < 64; d0 += 4) {
    f32x4 qf[4], pf[4];
#pragma unroll
    for (int i = 0; i < 4; i++) qf[i] = *(const f32x4*)&Qs[(r0 + i) * STR + d0];
#pragma unroll
    for (int dd = 0; dd < 4; dd++) pf[dd] = *(const f32x4*)&KPs[(d0 + dd) * STR + m0];
#pragma unroll
    for (int i = 0; i < 4; i++)
#pragma unroll
      for (int j = 0; j < 4; j++)
        accO[i][j] += qf[i][0] * pf[0][j] + qf[i][1] * pf[1][j] +
                      qf[i][2] * pf[2][j] + qf[i][3] * pf[3][j];
  }
  __syncthreads();  // B2: P reads done -> region becomes K
#pragma unroll
  for (int p = 0; p < 4; p++) {
    int f = p * 256 + tid, row = f >> 4, seg = (f & 15) * 4;
    *(f32x4*)&KPs[row * STR + seg] = kreg[p];
  }
  __syncthreads();  // B3

  // S = Q K^T: dot of natural-layout rows (no transpose needed)
  float accS[4][4] = {};
#pragma unroll 2
  for (int d0 = 0; d0 < 64; d0 += 4) {
    f32x4 qf[4], kf[4];
#pragma unroll
    for (int i = 0; i < 4; i++) qf[i] = *(const f32x4*)&Qs[(r0 + i) * STR + d0];
#pragma unroll
    for (int j = 0; j < 4; j++) kf[j] = *(const f32x4*)&KPs[(c0 + j) * STR + d0];
#pragma unroll
    for (int i = 0; i < 4; i++)
#pragma unroll
      for (int j = 0; j < 4; j++)
        accS[i][j] += qf[i][0] * kf[j][0] + qf[i][1] * kf[j][1] +
                      qf[i][2] * kf[j][2] + qf[i][3] * kf[j][3];
  }
  // causal mask (inclusive) + row-sum partials
  float dp[4];
#pragma unroll
  for (int i = 0; i < 4; i++) {
    dp[i] = 0.f;
#pragma unroll
    for (int j = 0; j < 4; j++) {
      float v = (c0 + j) <= (r0 + i) ? accS[i][j] : 0.f;
      accS[i][j] = v;
      dp[i] += v;
    }
  }
  __syncthreads();  // B4: Qs reads complete -> safe to overwrite with S
#pragma unroll
  for (int i = 0; i < 4; i++) {
    f32x4 sv = {accS[i][0], accS[i][1], accS[i][2], accS[i][3]};
    *(f32x4*)&Qs[(r0 + i) * STR + c0] = sv;
    denp[(r0 + i) * 16 + tx] = dp[i];
  }
  __syncthreads();  // B5
  // den finalize (1 wave) overlaps with S.V matmul (all waves)
  if (tid < 64) {
    float s = den[tid];
#pragma unroll
    for (int t = 0; t < 16; t++) s += denp[tid * 16 + t];
    den[tid] = s;
  }

  // accO += S . V
#pragma unroll 2
  for (int c4 = 0; c4 < 64; c4 += 4) {
    f32x4 sf[4], vf[4];
#pragma unroll
    for (int i = 0; i < 4; i++) sf[i] = *(const f32x4*)&Qs[(r0 + i) * STR + c4];
#pragma unroll
    for (int cc = 0; cc < 4; cc++) vf[cc] = *(const f32x4*)&Vs[(c4 + cc) * STR + m0];
#pragma unroll
    for (int i = 0; i < 4; i++)
#pragma unroll
      for (int j = 0; j < 4; j++)
        accO[i][j] += sf[i][0] * vf[0][j] + sf[i][1] * vf[1][j] +
                      sf[i][2] * vf[2][j] + sf[i][3] * vf[3][j];
  }
  __syncthreads();  // B6: den final visible

  // divide + store bf16 [T][DM]
#pragma unroll
  for (int i = 0; i < 4; i++) {
    const float inv = 1.f / den[r0 + i];
    short4v ov;
#pragma unroll
    for (int j = 0; j < 4; j++) ov[j] = f2b_bits(accO[i][j] * inv);
    *(short4v*)&O[(size_t)(c * CHUNK + r0 + i) * DM + h * 64 + m0] = ov;
  }
}

// ---------------------------------------------------------------------------
extern "C" void kernel_launch(void* const* d_in, const int* in_sizes, int n_in,
                              void* d_out, int out_size, void* d_ws, size_t ws_size,
                              hipStream_t stream) {
  (void)in_sizes; (void)n_in; (void)out_size; (void)ws_size;
  const float* x      = (const float*)d_in[0];
  const float* ln_g   = (const float*)d_in[1];
  const float* ln_b   = (const float*)d_in[2];
  const float* qkv_w  = (const float*)d_in[3];
  const float* qkv_b  = (const float*)d_in[4];
  const float* gate_w = (const float*)d_in[5];
  const float* gate_b = (const float*)d_in[6];
  const float* proj_w = (const float*)d_in[7];
  const float* proj_b = (const float*)d_in[8];
  float* out = (float*)d_out;

  char* ws = (char*)d_ws;
  size_t off = 0;
  auto alloc = [&](size_t bytes) {
    void* p = ws + off;
    off += (bytes + 255) & ~(size_t)255;
    return p;
  };
  bf16*  xn       = (bf16*)alloc((size_t)T_SEQ * DM * 2);
  bf16*  xbf      = (bf16*)alloc((size_t)T_SEQ * DM * 2);
  bf16*  wqkv     = (bf16*)alloc((size_t)3 * DM * DM * 2);
  bf16*  wgate    = (bf16*)alloc((size_t)DM * DM * 2);
  bf16*  wproj    = (bf16*)alloc((size_t)DM * DM * 2);
  float* gate_sig = (float*)alloc((size_t)T_SEQ * DM * 4);
  float* inv_den  = (float*)alloc((size_t)T_SEQ * 4);
  float* Qo       = (float*)alloc((size_t)T_SEQ * DM * 4);
  float* Ko       = (float*)alloc((size_t)T_SEQ * DM * 4);
  float* Vo       = (float*)alloc((size_t)T_SEQ * DM * 4);
  bf16*  Obuf     = (bf16*)alloc((size_t)T_SEQ * DM * 2);
  float* Skv      = (float*)alloc((size_t)NH * NCHUNK * 4096 * 4);
  float* Sk       = (float*)alloc((size_t)NH * NCHUNK * 64 * 4);

  const int n4_qkv = 3 * DM * DM / 4;
  const int n4_sq  = DM * DM / 4;
  f2b_kernel<<<(n4_qkv + 255) / 256, 256, 0, stream>>>(qkv_w, wqkv, n4_qkv);
  f2b_kernel<<<(n4_sq + 255) / 256, 256, 0, stream>>>(gate_w, wgate, n4_sq);
  f2b_kernel<<<(n4_sq + 255) / 256, 256, 0, stream>>>(proj_w, wproj, n4_sq);

  ln_kernel<<<T_SEQ, 256, 0, stream>>>(x, ln_g, ln_b, xn, xbf);
  gemm_bt<0><<<dim3(16, 8), 256, 0, stream>>>(xbf, wgate, gate_b, gate_sig, nullptr,
                                              nullptr, nullptr, nullptr, nullptr);
  gate_mean_kernel<<<T_SEQ, 256, 0, stream>>>(gate_sig, inv_den);
  gemm_bt<1><<<dim3(16, 24), 256, 0, stream>>>(xn, wqkv, qkv_b, gate_sig, inv_den,
                                               Qo, Ko, Vo, nullptr);
  chunk_sum_mm<<<NH * NCHUNK, 256, 0, stream>>>(Ko, Vo, Skv, Sk);
  scan_excl<<<260, 256, 0, stream>>>(Skv, Sk);
  attn_mm<<<NH * NCHUNK, 256, 0, stream>>>(Qo, Ko, Vo, Skv, Sk, Obuf);
  gemm_bt<2><<<dim3(16, 8), 256, 0, stream>>>(Obuf, wproj, proj_b, nullptr, nullptr,
                                              nullptr, nullptr, nullptr, out);
}

// Round 5
// 177.149 us; speedup vs baseline: 2.9754x; 1.1747x over previous
//
#include <hip/hip_runtime.h>
#include <hip/hip_bf16.h>
#include <math.h>

#define T_SEQ 2048
#define DM 1024
#define NH 16
#define DH 64
#define CHUNK 64
#define NCHUNK (T_SEQ / CHUNK)   // 32

typedef __hip_bfloat16 bf16;
typedef __attribute__((ext_vector_type(8))) short short8;
typedef __attribute__((ext_vector_type(4))) short short4v;
typedef __attribute__((ext_vector_type(4))) float f32x4;

static __device__ __forceinline__ short f2b_bits(float f) {
  bf16 t = __float2bfloat16(f);
  short s;
  __builtin_memcpy(&s, &t, 2);
  return s;
}

// gated ELU+1: elu(x)+1 = x>0 ? x+1 : exp(x)
static __device__ __forceinline__ float gelu1(float raw, float gate, float inv) {
  float x = raw * gate * inv;
  return x > 0.f ? x + 1.f : __expf(x);
}

// async global->LDS, 16B per lane; LDS dest must be wave-uniform base + lane*16
static __device__ __forceinline__ void gload16(const void* g, void* l) {
  __builtin_amdgcn_global_load_lds((const __attribute__((address_space(1))) void*)g,
                                   (__attribute__((address_space(3))) void*)l, 16, 0, 0);
}

// ---------------------------------------------------------------------------
// fp32 -> bf16 for all three weight tensors in one launch.
// ---------------------------------------------------------------------------
__global__ __launch_bounds__(256) void f2b3_kernel(const float* __restrict__ qkv,
                                                   const float* __restrict__ gw,
                                                   const float* __restrict__ pw,
                                                   bf16* __restrict__ oq,
                                                   bf16* __restrict__ og,
                                                   bf16* __restrict__ op) {
  constexpr int NQ = 3 * DM * DM / 4, NS = DM * DM / 4;
  int i = blockIdx.x * 256 + threadIdx.x;
  const float* src;
  bf16* dst;
  int j;
  if (i < NQ) { src = qkv; dst = oq; j = i; }
  else if (i < NQ + NS) { src = gw; dst = og; j = i - NQ; }
  else if (i < NQ + 2 * NS) { src = pw; dst = op; j = i - NQ - NS; }
  else return;
  float4 v = ((const float4*)src)[j];
  short4v s;
  s.x = f2b_bits(v.x); s.y = f2b_bits(v.y); s.z = f2b_bits(v.z); s.w = f2b_bits(v.w);
  *(short4v*)&dst[j * 4] = s;
}

// ---------------------------------------------------------------------------
// LayerNorm (fp32 in) -> xn bf16, plus bf16 copy of raw x for gate GEMM.
// ---------------------------------------------------------------------------
__global__ __launch_bounds__(256) void ln_kernel(const float* __restrict__ x,
                                                 const float* __restrict__ g,
                                                 const float* __restrict__ b,
                                                 bf16* __restrict__ xn,
                                                 bf16* __restrict__ xbf) {
  const int row = blockIdx.x;
  const float* xr = x + (size_t)row * DM;
  float vals[4];
  float s = 0.f, s2 = 0.f;
#pragma unroll
  for (int i = 0; i < 4; i++) {
    float v = xr[threadIdx.x + i * 256];
    vals[i] = v;
    s += v;
    s2 += v * v;
  }
#pragma unroll
  for (int m = 1; m < 64; m <<= 1) {
    s += __shfl_xor(s, m, 64);
    s2 += __shfl_xor(s2, m, 64);
  }
  __shared__ float red[8];
  const int wid = threadIdx.x >> 6;
  if ((threadIdx.x & 63) == 0) {
    red[wid] = s;
    red[4 + wid] = s2;
  }
  __syncthreads();
  s = red[0] + red[1] + red[2] + red[3];
  s2 = red[4] + red[5] + red[6] + red[7];
  const float mean = s * (1.f / DM);
  const float var = s2 * (1.f / DM) - mean * mean;
  const float rstd = rsqrtf(var + 1e-5f);
#pragma unroll
  for (int i = 0; i < 4; i++) {
    int idx = threadIdx.x + i * 256;
    float v = (vals[i] - mean) * rstd * g[idx] + b[idx];
    xn[(size_t)row * DM + idx] = __float2bfloat16(v);
    xbf[(size_t)row * DM + idx] = __float2bfloat16(vals[i]);
  }
}

// ---------------------------------------------------------------------------
// Fused gate+qkv GEMM, tile 128x128, BK=64 (two 32-sections per barrier pair).
// grid (16, 32): y<8 -> gate (A=xbf, W=wg) -> sigmoid to gate_sig[T][DM];
//                y>=8 -> qkv (A=xn, W=wq) -> RAW biased q,k scatter [H][T][DH],
//                v scatter [H][T][DH]. Gating applied later in consumers.
// ---------------------------------------------------------------------------
__global__ __launch_bounds__(256) void gemm_gateqkv(
    const bf16* __restrict__ xbf, const bf16* __restrict__ xn,
    const bf16* __restrict__ wg, const bf16* __restrict__ wq,
    const float* __restrict__ gate_b, const float* __restrict__ qkv_b,
    float* __restrict__ gate_sig, float* __restrict__ Qraw,
    float* __restrict__ Kraw, float* __restrict__ Vo) {
  constexpr int K = 1024;
  __shared__ __align__(16) short As[2 * 128 * 32];
  __shared__ __align__(16) short Bs[2 * 128 * 32];

  const int tid = threadIdx.x;
  const int wid = tid >> 6, lane = tid & 63;
  const int wm = wid >> 1, wn = wid & 1;
  const int lm = lane & 15, quad = lane >> 4;

  const bool isGate = blockIdx.y < 8;
  const int m0 = blockIdx.x * 128;
  const int n0 = isGate ? blockIdx.y * 128 : (blockIdx.y - 8) * 128;
  const short* Ag = (const short*)(isGate ? xbf : xn);
  const short* Wg = (const short*)(isGate ? wg : wq);
  const float* bias = isGate ? gate_b : qkv_b;

  f32x4 zero = {0.f, 0.f, 0.f, 0.f};
  f32x4 acc[4][4];
#pragma unroll
  for (int i = 0; i < 4; i++)
#pragma unroll
    for (int j = 0; j < 4; j++) acc[i][j] = zero;

  for (int kb = 0; kb < K; kb += 64) {
    __syncthreads();
#pragma unroll
    for (int sec = 0; sec < 2; sec++) {
#pragma unroll
      for (int it = 0; it < 2; it++) {
        const int idx = it * 256 + tid;
        const int row = idx >> 2, seg = (idx & 3) * 8;
        gload16(&Ag[(size_t)(m0 + row) * K + kb + sec * 32 + seg],
                &As[sec * 4096 + (it * 256 + wid * 64) * 8]);
        gload16(&Wg[(size_t)(n0 + row) * K + kb + sec * 32 + seg],
                &Bs[sec * 4096 + (it * 256 + wid * 64) * 8]);
      }
    }
    __syncthreads();
#pragma unroll
    for (int sec = 0; sec < 2; sec++) {
      short8 afr[4], bfr[4];
#pragma unroll
      for (int i = 0; i < 4; i++) {
        afr[i] = *(const short8*)&As[sec * 4096 + (wm * 64 + i * 16 + lm) * 32 + quad * 8];
        bfr[i] = *(const short8*)&Bs[sec * 4096 + (wn * 64 + i * 16 + lm) * 32 + quad * 8];
      }
#pragma unroll
      for (int i = 0; i < 4; i++)
#pragma unroll
        for (int j = 0; j < 4; j++)
          acc[i][j] = __builtin_amdgcn_mfma_f32_16x16x32_bf16(afr[i], bfr[j], acc[i][j], 0, 0, 0);
    }
  }

  // epilogue: C/D layout col = lane&15, row = quad*4 + r
#pragma unroll
  for (int i = 0; i < 4; i++) {
    const int rbase = m0 + wm * 64 + i * 16 + quad * 4;
#pragma unroll
    for (int j = 0; j < 4; j++) {
      const int col = n0 + wn * 64 + j * 16 + lm;
      const float bval = bias[col];
#pragma unroll
      for (int r = 0; r < 4; r++) {
        const int row = rbase + r;
        float v = acc[i][j][r] + bval;
        if (isGate) {
          gate_sig[(size_t)row * DM + col] = 1.f / (1.f + __expf(-v));
        } else if (col < DM) {
          const int d = col;
          Qraw[((size_t)(d >> 6) * T_SEQ + row) * DH + (d & 63)] = v;
        } else if (col < 2 * DM) {
          const int d = col - DM;
          Kraw[((size_t)(d >> 6) * T_SEQ + row) * DH + (d & 63)] = v;
        } else {
          const int d = col - 2 * DM;
          Vo[((size_t)(d >> 6) * T_SEQ + row) * DH + (d & 63)] = v;
        }
      }
    }
  }
}

// ---------------------------------------------------------------------------
// Proj GEMM: tile 64x128, BK=64, grid (32, 8) = 256 blocks. fp32 out.
// ---------------------------------------------------------------------------
__global__ __launch_bounds__(256) void gemm_proj(const bf16* __restrict__ A,
                                                 const bf16* __restrict__ W,
                                                 const float* __restrict__ bias,
                                                 float* __restrict__ Cout) {
  constexpr int K = 1024;
  __shared__ __align__(16) short As[2 * 64 * 32];
  __shared__ __align__(16) short Bs[2 * 128 * 32];

  const int tid = threadIdx.x;
  const int wid = tid >> 6, lane = tid & 63;
  const int wm = wid >> 1, wn = wid & 1;   // wave tile 32(m) x 64(n)
  const int lm = lane & 15, quad = lane >> 4;

  const int m0 = blockIdx.x * 64;
  const int n0 = blockIdx.y * 128;
  const short* Ag = (const short*)A;
  const short* Wg = (const short*)W;

  f32x4 zero = {0.f, 0.f, 0.f, 0.f};
  f32x4 acc[2][4];
#pragma unroll
  for (int i = 0; i < 2; i++)
#pragma unroll
    for (int j = 0; j < 4; j++) acc[i][j] = zero;

  for (int kb = 0; kb < K; kb += 64) {
    __syncthreads();
#pragma unroll
    for (int sec = 0; sec < 2; sec++) {
      {  // A: 64 rows x 32 shorts per section = one 256-lane issue
        const int row = tid >> 2, seg = (tid & 3) * 8;
        gload16(&Ag[(size_t)(m0 + row) * K + kb + sec * 32 + seg],
                &As[sec * 2048 + (wid * 64) * 8]);
      }
#pragma unroll
      for (int it = 0; it < 2; it++) {
        const int idx = it * 256 + tid;
        const int row = idx >> 2, seg = (idx & 3) * 8;
        gload16(&Wg[(size_t)(n0 + row) * K + kb + sec * 32 + seg],
                &Bs[sec * 4096 + (it * 256 + wid * 64) * 8]);
      }
    }
    __syncthreads();
#pragma unroll
    for (int sec = 0; sec < 2; sec++) {
      short8 afr[2], bfr[4];
#pragma unroll
      for (int i = 0; i < 2; i++)
        afr[i] = *(const short8*)&As[sec * 2048 + (wm * 32 + i * 16 + lm) * 32 + quad * 8];
#pragma unroll
      for (int j = 0; j < 4; j++)
        bfr[j] = *(const short8*)&Bs[sec * 4096 + (wn * 64 + j * 16 + lm) * 32 + quad * 8];
#pragma unroll
      for (int i = 0; i < 2; i++)
#pragma unroll
        for (int j = 0; j < 4; j++)
          acc[i][j] = __builtin_amdgcn_mfma_f32_16x16x32_bf16(afr[i], bfr[j], acc[i][j], 0, 0, 0);
    }
  }
#pragma unroll
  for (int i = 0; i < 2; i++) {
    const int rbase = m0 + wm * 32 + i * 16 + quad * 4;
#pragma unroll
    for (int j = 0; j < 4; j++) {
      const int col = n0 + wn * 64 + j * 16 + lm;
      const float bval = bias[col];
#pragma unroll
      for (int r = 0; r < 4; r++)
        Cout[(size_t)(rbase + r) * DM + col] = acc[i][j][r] + bval;
    }
  }
}

// ---------------------------------------------------------------------------
// Gate row mean -> inv_den[row] = 1/(mean + EPS_GATE)
// ---------------------------------------------------------------------------
__global__ __launch_bounds__(256) void gate_mean_kernel(const float* __restrict__ gate_sig,
                                                        float* __restrict__ inv_den) {
  const int row = blockIdx.x;
  float s = 0.f;
  for (int i = threadIdx.x; i < DM; i += 256) s += gate_sig[(size_t)row * DM + i];
#pragma unroll
  for (int m = 1; m < 64; m <<= 1) s += __shfl_xor(s, m, 64);
  __shared__ float red[4];
  if ((threadIdx.x & 63) == 0) red[threadIdx.x >> 6] = s;
  __syncthreads();
  if (threadIdx.x == 0) {
    float tot = red[0] + red[1] + red[2] + red[3];
    inv_den[row] = 1.f / (tot * (1.f / DM) + 1e-5f);
  }
}

// ---------------------------------------------------------------------------
// Pass A: per (h,c) Skv_c = K_g^T V with K gated+ELU'd on the fly during
// staging (from raw k + gate_sig + inv_den). Sk_c = col sums of gated K.
// ---------------------------------------------------------------------------
__global__ __launch_bounds__(256, 2) void chunk_sum_mm(const float* __restrict__ Kraw,
                                                       const float* __restrict__ gate_sig,
                                                       const float* __restrict__ inv_den,
                                                       const float* __restrict__ Vo,
                                                       float* __restrict__ Skv,
                                                       float* __restrict__ Sk) {
  constexpr int STR = 68;
  __shared__ __align__(16) float Ks2[64 * STR];
  __shared__ __align__(16) float Vs2[64 * STR];
  const int b = blockIdx.x;
  const int h = b >> 5, c = b & 31;
  const int tid = threadIdx.x;
  const int ty = tid >> 4, tx = tid & 15;
  const int d0 = ty * 4, m0 = tx * 4;
  const int t0 = c * CHUNK;
  const size_t cb = ((size_t)h * T_SEQ + t0) * DH;
  const float* Kg = Kraw + cb;
  const float* Vg = Vo + cb;
#pragma unroll
  for (int p = 0; p < 4; p++) {
    int f = p * 256 + tid, row = f >> 4, seg = (f & 15) * 4;
    const int t = t0 + row;
    f32x4 kr = *(const f32x4*)&Kg[row * 64 + seg];
    f32x4 gr = *(const f32x4*)&gate_sig[(size_t)t * DM + h * 64 + seg];
    const float inv = inv_den[t];
    f32x4 kgv;
#pragma unroll
    for (int e = 0; e < 4; e++) kgv[e] = gelu1(kr[e], gr[e], inv);
    *(f32x4*)&Ks2[row * STR + seg] = kgv;
    *(f32x4*)&Vs2[row * STR + seg] = *(const f32x4*)&Vg[row * 64 + seg];
  }
  __syncthreads();
  float acc[4][4] = {};
#pragma unroll 4
  for (int s = 0; s < 64; s++) {
    f32x4 kf = *(const f32x4*)&Ks2[s * STR + d0];
    f32x4 vf = *(const f32x4*)&Vs2[s * STR + m0];
#pragma unroll
    for (int i = 0; i < 4; i++)
#pragma unroll
      for (int j = 0; j < 4; j++) acc[i][j] += kf[i] * vf[j];
  }
  float* outp = Skv + (size_t)b * 4096;
#pragma unroll
  for (int i = 0; i < 4; i++) {
    f32x4 o = {acc[i][0], acc[i][1], acc[i][2], acc[i][3]};
    *(f32x4*)&outp[(d0 + i) * 64 + m0] = o;
  }
  if (tid < 64) {
    float ss = 0.f;
#pragma unroll 4
    for (int s = 0; s < 64; s++) ss += Ks2[s * STR + tid];
    Sk[b * 64 + tid] = ss;
  }
}

// ---------------------------------------------------------------------------
// Pass B: exclusive prefix over chunks, one thread per (h,e) chain.
// ---------------------------------------------------------------------------
__global__ __launch_bounds__(256) void scan_excl(float* __restrict__ Skv,
                                                 float* __restrict__ Sk) {
  const int bid = blockIdx.x, tid = threadIdx.x;
  if (bid < 256) {
    const int id = bid * 256 + tid;
    const int h = id >> 12, e = id & 4095;
    float* base = Skv + (size_t)h * NCHUNK * 4096 + e;
    float v[NCHUNK];
#pragma unroll
    for (int c = 0; c < NCHUNK; c++) v[c] = base[(size_t)c * 4096];
    float run = 0.f;
#pragma unroll
    for (int c = 0; c < NCHUNK; c++) {
      float t = v[c];
      base[(size_t)c * 4096] = run;
      run += t;
    }
  } else {
    const int id = (bid - 256) * 256 + tid;
    const int h = id >> 6, e = id & 63;
    float* base = Sk + (size_t)h * NCHUNK * 64 + e;
    float v[NCHUNK];
#pragma unroll
    for (int c = 0; c < NCHUNK; c++) v[c] = base[c * 64];
    float run = 0.f;
#pragma unroll
    for (int c = 0; c < NCHUNK; c++) {
      float t = v[c];
      base[c * 64] = run;
      run += t;
    }
  }
}

// ---------------------------------------------------------------------------
// Pass C: per (h,c): accO = Q.P ; S = Q K^T (causal) ; accO += S.V ;
// den = q.Skp + rowsum(S). Gating+ELU applied to Q,K during staging.
// All in-loop operands from LDS; P/K share one region.
// ---------------------------------------------------------------------------
__global__ __launch_bounds__(256, 2) void attn_mm(const float* __restrict__ Qraw,
                                                  const float* __restrict__ Kraw,
                                                  const float* __restrict__ gate_sig,
                                                  const float* __restrict__ inv_den,
                                                  const float* __restrict__ Vo,
                                                  const float* __restrict__ Skv,
                                                  const float* __restrict__ Sk,
                                                  bf16* __restrict__ O) {
  constexpr int STR = 68;
  __shared__ __align__(16) float Qs[64 * STR];   // gated Q, later S
  __shared__ __align__(16) float Vs[64 * STR];
  __shared__ __align__(16) float KPs[64 * STR];  // P phase 1, gated K phase 2
  __shared__ float denp[64 * 16];
  __shared__ float skp[64];
  __shared__ float den[64];
  const int b = blockIdx.x;
  const int h = b >> 5, c = b & 31;
  const int tid = threadIdx.x;
  const int ty = tid >> 4, tx = tid & 15;
  const int r0 = ty * 4, c0 = tx * 4, m0 = tx * 4;
  const int t0 = c * CHUNK;
  const size_t cb = ((size_t)h * T_SEQ + t0) * DH;
  const float* Qg = Qraw + cb;
  const float* Kg = Kraw + cb;
  const float* Vg = Vo + cb;
  const float* Pg = Skv + (size_t)b * 4096;

  // K prefetch (raw + gate + inv) into registers; consumed in phase 2
  f32x4 kreg[4], greg[4];
  float ireg[4];
#pragma unroll
  for (int p = 0; p < 4; p++) {
    int f = p * 256 + tid, row = f >> 4, seg = (f & 15) * 4;
    kreg[p] = *(const f32x4*)&Kg[row * 64 + seg];
    greg[p] = *(const f32x4*)&gate_sig[(size_t)(t0 + row) * DM + h * 64 + seg];
    ireg[p] = inv_den[t0 + row];
  }
  // stage gated Q, V, P (coalesced)
#pragma unroll
  for (int p = 0; p < 4; p++) {
    int f = p * 256 + tid, row = f >> 4, seg = (f & 15) * 4;
    f32x4 qr = *(const f32x4*)&Qg[row * 64 + seg];
    f32x4 gq = *(const f32x4*)&gate_sig[(size_t)(t0 + row) * DM + h * 64 + seg];
    const float inv = inv_den[t0 + row];
    f32x4 qgv;
#pragma unroll
    for (int e = 0; e < 4; e++) qgv[e] = gelu1(qr[e], gq[e], inv);
    *(f32x4*)&Qs[row * STR + seg] = qgv;
    *(f32x4*)&Vs[row * STR + seg] = *(const f32x4*)&Vg[row * 64 + seg];
    *(f32x4*)&KPs[row * STR + seg] = *(const f32x4*)&Pg[row * 64 + seg];
  }
  if (tid < 64) skp[tid] = Sk[b * 64 + tid];
  __syncthreads();  // B1

  // den init: q . Sk_prefix + EPS_DEN
  if (tid < 64) {
    float s = 1e-5f;
#pragma unroll 4
    for (int d = 0; d < 64; d++) s += Qs[tid * STR + d] * skp[d];
    den[tid] = s;
  }

  // accO = Q . P
  float accO[4][4] = {};
#pragma unroll 2
  for (int d0 = 0; d0 < 64; d0 += 4) {
    f32x4 qf[4], pf[4];
#pragma unroll
    for (int i = 0; i < 4; i++) qf[i] = *(const f32x4*)&Qs[(r0 + i) * STR + d0];
#pragma unroll
    for (int dd = 0; dd < 4; dd++) pf[dd] = *(const f32x4*)&KPs[(d0 + dd) * STR + m0];
#pragma unroll
    for (int i = 0; i < 4; i++)
#pragma unroll
      for (int j = 0; j < 4; j++)
        accO[i][j] += qf[i][0] * pf[0][j] + qf[i][1] * pf[1][j] +
                      qf[i][2] * pf[2][j] + qf[i][3] * pf[3][j];
  }
  __syncthreads();  // B2: P reads done -> region becomes gated K
#pragma unroll
  for (int p = 0; p < 4; p++) {
    int f = p * 256 + tid, row = f >> 4, seg = (f & 15) * 4;
    f32x4 kgv;
#pragma unroll
    for (int e = 0; e < 4; e++) kgv[e] = gelu1(kreg[p][e], greg[p][e], ireg[p]);
    *(f32x4*)&KPs[row * STR + seg] = kgv;
  }
  __syncthreads();  // B3

  // S = Q K^T (row-dot, natural layout)
  float accS[4][4] = {};
#pragma unroll 2
  for (int d0 = 0; d0 < 64; d0 += 4) {
    f32x4 qf[4], kf[4];
#pragma unroll
    for (int i = 0; i < 4; i++) qf[i] = *(const f32x4*)&Qs[(r0 + i) * STR + d0];
#pragma unroll
    for (int j = 0; j < 4; j++) kf[j] = *(const f32x4*)&KPs[(c0 + j) * STR + d0];
#pragma unroll
    for (int i = 0; i < 4; i++)
#pragma unroll
      for (int j = 0; j < 4; j++)
        accS[i][j] += qf[i][0] * kf[j][0] + qf[i][1] * kf[j][1] +
                      qf[i][2] * kf[j][2] + qf[i][3] * kf[j][3];
  }
  // causal mask (inclusive) + row-sum partials
  float dp[4];
#pragma unroll
  for (int i = 0; i < 4; i++) {
    dp[i] = 0.f;
#pragma unroll
    for (int j = 0; j < 4; j++) {
      float v = (c0 + j) <= (r0 + i) ? accS[i][j] : 0.f;
      accS[i][j] = v;
      dp[i] += v;
    }
  }
  __syncthreads();  // B4: Qs reads complete -> overwrite with S
#pragma unroll
  for (int i = 0; i < 4; i++) {
    f32x4 sv = {accS[i][0], accS[i][1], accS[i][2], accS[i][3]};
    *(f32x4*)&Qs[(r0 + i) * STR + c0] = sv;
    denp[(r0 + i) * 16 + tx] = dp[i];
  }
  __syncthreads();  // B5
  if (tid < 64) {
    float s = den[tid];
#pragma unroll
    for (int t = 0; t < 16; t++) s += denp[tid * 16 + t];
    den[tid] = s;
  }

  // accO += S . V
#pragma unroll 2
  for (int c4 = 0; c4 < 64; c4 += 4) {
    f32x4 sf[4], vf[4];
#pragma unroll
    for (int i = 0; i < 4; i++) sf[i] = *(const f32x4*)&Qs[(r0 + i) * STR + c4];
#pragma unroll
    for (int cc = 0; cc < 4; cc++) vf[cc] = *(const f32x4*)&Vs[(c4 + cc) * STR + m0];
#pragma unroll
    for (int i = 0; i < 4; i++)
#pragma unroll
      for (int j = 0; j < 4; j++)
        accO[i][j] += sf[i][0] * vf[0][j] + sf[i][1] * vf[1][j] +
                      sf[i][2] * vf[2][j] + sf[i][3] * vf[3][j];
  }
  __syncthreads();  // B6: den final visible

#pragma unroll
  for (int i = 0; i < 4; i++) {
    const float inv = 1.f / den[r0 + i];
    short4v ov;
#pragma unroll
    for (int j = 0; j < 4; j++) ov[j] = f2b_bits(accO[i][j] * inv);
    *(short4v*)&O[(size_t)(t0 + r0 + i) * DM + h * 64 + m0] = ov;
  }
}

// ---------------------------------------------------------------------------
extern "C" void kernel_launch(void* const* d_in, const int* in_sizes, int n_in,
                              void* d_out, int out_size, void* d_ws, size_t ws_size,
                              hipStream_t stream) {
  (void)in_sizes; (void)n_in; (void)out_size; (void)ws_size;
  const float* x      = (const float*)d_in[0];
  const float* ln_g   = (const float*)d_in[1];
  const float* ln_b   = (const float*)d_in[2];
  const float* qkv_w  = (const float*)d_in[3];
  const float* qkv_b  = (const float*)d_in[4];
  const float* gate_w = (const float*)d_in[5];
  const float* gate_b = (const float*)d_in[6];
  const float* proj_w = (const float*)d_in[7];
  const float* proj_b = (const float*)d_in[8];
  float* out = (float*)d_out;

  char* ws = (char*)d_ws;
  size_t off = 0;
  auto alloc = [&](size_t bytes) {
    void* p = ws + off;
    off += (bytes + 255) & ~(size_t)255;
    return p;
  };
  bf16*  xn       = (bf16*)alloc((size_t)T_SEQ * DM * 2);
  bf16*  xbf      = (bf16*)alloc((size_t)T_SEQ * DM * 2);
  bf16*  wqkv     = (bf16*)alloc((size_t)3 * DM * DM * 2);
  bf16*  wgate    = (bf16*)alloc((size_t)DM * DM * 2);
  bf16*  wproj    = (bf16*)alloc((size_t)DM * DM * 2);
  float* gate_sig = (float*)alloc((size_t)T_SEQ * DM * 4);
  float* inv_den  = (float*)alloc((size_t)T_SEQ * 4);
  float* Qraw     = (float*)alloc((size_t)T_SEQ * DM * 4);
  float* Kraw     = (float*)alloc((size_t)T_SEQ * DM * 4);
  float* Vo       = (float*)alloc((size_t)T_SEQ * DM * 4);
  bf16*  Obuf     = (bf16*)alloc((size_t)T_SEQ * DM * 2);
  float* Skv      = (float*)alloc((size_t)NH * NCHUNK * 4096 * 4);
  float* Sk       = (float*)alloc((size_t)NH * NCHUNK * 64 * 4);

  const int n4_total = (3 + 1 + 1) * DM * DM / 4;
  f2b3_kernel<<<(n4_total + 255) / 256, 256, 0, stream>>>(qkv_w, gate_w, proj_w,
                                                          wqkv, wgate, wproj);
  ln_kernel<<<T_SEQ, 256, 0, stream>>>(x, ln_g, ln_b, xn, xbf);
  gemm_gateqkv<<<dim3(16, 32), 256, 0, stream>>>(xbf, xn, wgate, wqkv, gate_b, qkv_b,
                                                 gate_sig, Qraw, Kraw, Vo);
  gate_mean_kernel<<<T_SEQ, 256, 0, stream>>>(gate_sig, inv_den);
  chunk_sum_mm<<<NH * NCHUNK, 256, 0, stream>>>(Kraw, gate_sig, inv_den, Vo, Skv, Sk);
  scan_excl<<<260, 256, 0, stream>>>(Skv, Sk);
  attn_mm<<<NH * NCHUNK, 256, 0, stream>>>(Qraw, Kraw, gate_sig, inv_den, Vo, Skv, Sk, Obuf);
  gemm_proj<<<dim3(32, 8), 256, 0, stream>>>(Obuf, wproj, proj_b, out);
}

// Round 6
// 165.751 us; speedup vs baseline: 3.1800x; 1.0688x over previous
//
#include <hip/hip_runtime.h>
#include <hip/hip_bf16.h>
#include <math.h>

#define T_SEQ 2048
#define DM 1024
#define NH 16
#define DH 64
#define CHUNK 64
#define NCHUNK (T_SEQ / CHUNK)   // 32

typedef __hip_bfloat16 bf16;
typedef __attribute__((ext_vector_type(8))) short short8;
typedef __attribute__((ext_vector_type(4))) short short4v;
typedef __attribute__((ext_vector_type(4))) float f32x4;

static __device__ __forceinline__ short f2b_bits(float f) {
  bf16 t = __float2bfloat16(f);
  short s;
  __builtin_memcpy(&s, &t, 2);
  return s;
}
static __device__ __forceinline__ float b2f(short s) {
  unsigned int u = ((unsigned int)(unsigned short)s) << 16;
  float f;
  __builtin_memcpy(&f, &u, 4);
  return f;
}

// gated ELU+1: elu(x)+1 = x>0 ? x+1 : exp(x)
static __device__ __forceinline__ float gelu1(float raw, float gate, float inv) {
  float x = raw * gate * inv;
  return x > 0.f ? x + 1.f : __expf(x);
}

// async global->LDS, 16B per lane; LDS dest must be wave-uniform base + lane*16
static __device__ __forceinline__ void gload16(const void* g, void* l) {
  __builtin_amdgcn_global_load_lds((const __attribute__((address_space(1))) void*)g,
                                   (__attribute__((address_space(3))) void*)l, 16, 0, 0);
}

// ---------------------------------------------------------------------------
// prep: blocks 0..2047 = LayerNorm rows (also zero gate_accum in blocks 0..7);
//       blocks 2048..  = fp32->bf16 weight conversion (qkv|gate|proj).
// ---------------------------------------------------------------------------
#define PREP_WBLOCKS (5 * DM * DM / 4 / 256)   // 5120
__global__ __launch_bounds__(256) void prep_kernel(
    const float* __restrict__ x, const float* __restrict__ g,
    const float* __restrict__ b, const float* __restrict__ qkv_w,
    const float* __restrict__ gate_w, const float* __restrict__ proj_w,
    bf16* __restrict__ xn, bf16* __restrict__ xbf,
    bf16* __restrict__ wqkv, bf16* __restrict__ wgate, bf16* __restrict__ wproj,
    float* __restrict__ gate_accum) {
  const int blk = blockIdx.x;
  if (blk < T_SEQ) {
    const int row = blk;
    if (row < 8) gate_accum[row * 256 + threadIdx.x] = 0.f;
    const float* xr = x + (size_t)row * DM;
    float vals[4];
    float s = 0.f, s2 = 0.f;
#pragma unroll
    for (int i = 0; i < 4; i++) {
      float v = xr[threadIdx.x + i * 256];
      vals[i] = v;
      s += v;
      s2 += v * v;
    }
#pragma unroll
    for (int m = 1; m < 64; m <<= 1) {
      s += __shfl_xor(s, m, 64);
      s2 += __shfl_xor(s2, m, 64);
    }
    __shared__ float red[8];
    const int wid = threadIdx.x >> 6;
    if ((threadIdx.x & 63) == 0) {
      red[wid] = s;
      red[4 + wid] = s2;
    }
    __syncthreads();
    s = red[0] + red[1] + red[2] + red[3];
    s2 = red[4] + red[5] + red[6] + red[7];
    const float mean = s * (1.f / DM);
    const float var = s2 * (1.f / DM) - mean * mean;
    const float rstd = rsqrtf(var + 1e-5f);
#pragma unroll
    for (int i = 0; i < 4; i++) {
      int idx = threadIdx.x + i * 256;
      float v = (vals[i] - mean) * rstd * g[idx] + b[idx];
      xn[(size_t)row * DM + idx] = __float2bfloat16(v);
      xbf[(size_t)row * DM + idx] = __float2bfloat16(vals[i]);
    }
  } else {
    constexpr int NQ = 3 * DM * DM / 4, NS = DM * DM / 4;
    int i = (blk - T_SEQ) * 256 + threadIdx.x;
    const float* src;
    bf16* dst;
    int j;
    if (i < NQ) { src = qkv_w; dst = wqkv; j = i; }
    else if (i < NQ + NS) { src = gate_w; dst = wgate; j = i - NQ; }
    else { src = proj_w; dst = wproj; j = i - NQ - NS; }
    float4 v = ((const float4*)src)[j];
    short4v sv;
    sv.x = f2b_bits(v.x); sv.y = f2b_bits(v.y); sv.z = f2b_bits(v.z); sv.w = f2b_bits(v.w);
    *(short4v*)&dst[j * 4] = sv;
  }
}

// ---------------------------------------------------------------------------
// Fused gate+qkv GEMM, tile 128x128, BK=64.
// grid (16, 32): y<8 -> gate: sigmoid -> gate_sig (bf16) + row-sum atomics
//                into gate_accum (LDS-reduced, 1 atomic/row/block);
//                y>=8 -> qkv: RAW biased q,k,v scatter [H][T][DH] bf16.
// ---------------------------------------------------------------------------
__global__ __launch_bounds__(256) void gemm_gateqkv(
    const bf16* __restrict__ xbf, const bf16* __restrict__ xn,
    const bf16* __restrict__ wg, const bf16* __restrict__ wq,
    const float* __restrict__ gate_b, const float* __restrict__ qkv_b,
    short* __restrict__ Gb, float* __restrict__ gate_accum,
    short* __restrict__ Qb, short* __restrict__ Kb, short* __restrict__ Vb) {
  constexpr int K = 1024;
  __shared__ __align__(16) short As[2 * 128 * 32];
  __shared__ __align__(16) short Bs[2 * 128 * 32];

  const int tid = threadIdx.x;
  const int wid = tid >> 6, lane = tid & 63;
  const int wm = wid >> 1, wn = wid & 1;
  const int lm = lane & 15, quad = lane >> 4;

  const bool isGate = blockIdx.y < 8;
  const int m0 = blockIdx.x * 128;
  const int n0 = isGate ? blockIdx.y * 128 : (blockIdx.y - 8) * 128;
  const short* Ag = (const short*)(isGate ? xbf : xn);
  const short* Wg = (const short*)(isGate ? wg : wq);

  f32x4 zero = {0.f, 0.f, 0.f, 0.f};
  f32x4 acc[4][4];
#pragma unroll
  for (int i = 0; i < 4; i++)
#pragma unroll
    for (int j = 0; j < 4; j++) acc[i][j] = zero;

  for (int kb = 0; kb < K; kb += 64) {
    __syncthreads();
#pragma unroll
    for (int sec = 0; sec < 2; sec++) {
#pragma unroll
      for (int it = 0; it < 2; it++) {
        const int idx = it * 256 + tid;
        const int row = idx >> 2, seg = (idx & 3) * 8;
        gload16(&Ag[(size_t)(m0 + row) * K + kb + sec * 32 + seg],
                &As[sec * 4096 + (it * 256 + wid * 64) * 8]);
        gload16(&Wg[(size_t)(n0 + row) * K + kb + sec * 32 + seg],
                &Bs[sec * 4096 + (it * 256 + wid * 64) * 8]);
      }
    }
    __syncthreads();
#pragma unroll
    for (int sec = 0; sec < 2; sec++) {
      short8 afr[4], bfr[4];
#pragma unroll
      for (int i = 0; i < 4; i++) {
        afr[i] = *(const short8*)&As[sec * 4096 + (wm * 64 + i * 16 + lm) * 32 + quad * 8];
        bfr[i] = *(const short8*)&Bs[sec * 4096 + (wn * 64 + i * 16 + lm) * 32 + quad * 8];
      }
#pragma unroll
      for (int i = 0; i < 4; i++)
#pragma unroll
        for (int j = 0; j < 4; j++)
          acc[i][j] = __builtin_amdgcn_mfma_f32_16x16x32_bf16(afr[i], bfr[j], acc[i][j], 0, 0, 0);
    }
  }

  // epilogue: C/D layout col = lane&15, row = quad*4 + r
  if (isGate) {
    float* red = (float*)As;   // 128 rows x 32 slots = 16 KB
    __syncthreads();           // MFMA LDS reads done -> safe to reuse As
#pragma unroll
    for (int i = 0; i < 4; i++) {
#pragma unroll
      for (int r = 0; r < 4; r++) {
        const int rowl = wm * 64 + i * 16 + quad * 4 + r;
        const int row = m0 + rowl;
        float rp = 0.f;
#pragma unroll
        for (int j = 0; j < 4; j++) {
          const int col = n0 + wn * 64 + j * 16 + lm;
          float v = acc[i][j][r] + gate_b[col];
          float sig = 1.f / (1.f + __expf(-v));
          Gb[(size_t)row * DM + col] = f2b_bits(sig);
          rp += sig;
        }
        red[rowl * 32 + wn * 16 + lm] = rp;
      }
    }
    __syncthreads();
    if (tid < 128) {
      float s = 0.f;
#pragma unroll
      for (int t2 = 0; t2 < 32; t2++) s += red[tid * 32 + t2];
      atomicAdd(&gate_accum[m0 + tid], s);
    }
  } else {
#pragma unroll
    for (int i = 0; i < 4; i++) {
      const int rbase = m0 + wm * 64 + i * 16 + quad * 4;
#pragma unroll
      for (int j = 0; j < 4; j++) {
        const int col = n0 + wn * 64 + j * 16 + lm;
        const float bval = qkv_b[col];
#pragma unroll
        for (int r = 0; r < 4; r++) {
          const int row = rbase + r;
          const short bv = f2b_bits(acc[i][j][r] + bval);
          if (col < DM) {
            const int d = col;
            Qb[((size_t)(d >> 6) * T_SEQ + row) * DH + (d & 63)] = bv;
          } else if (col < 2 * DM) {
            const int d = col - DM;
            Kb[((size_t)(d >> 6) * T_SEQ + row) * DH + (d & 63)] = bv;
          } else {
            const int d = col - 2 * DM;
            Vb[((size_t)(d >> 6) * T_SEQ + row) * DH + (d & 63)] = bv;
          }
        }
      }
    }
  }
}

// ---------------------------------------------------------------------------
// Proj GEMM: tile 64x128, BK=64, grid (32, 8) = 256 blocks. fp32 out.
// ---------------------------------------------------------------------------
__global__ __launch_bounds__(256) void gemm_proj(const bf16* __restrict__ A,
                                                 const bf16* __restrict__ W,
                                                 const float* __restrict__ bias,
                                                 float* __restrict__ Cout) {
  constexpr int K = 1024;
  __shared__ __align__(16) short As[2 * 64 * 32];
  __shared__ __align__(16) short Bs[2 * 128 * 32];

  const int tid = threadIdx.x;
  const int wid = tid >> 6, lane = tid & 63;
  const int wm = wid >> 1, wn = wid & 1;   // wave tile 32(m) x 64(n)
  const int lm = lane & 15, quad = lane >> 4;

  const int m0 = blockIdx.x * 64;
  const int n0 = blockIdx.y * 128;
  const short* Ag = (const short*)A;
  const short* Wg = (const short*)W;

  f32x4 zero = {0.f, 0.f, 0.f, 0.f};
  f32x4 acc[2][4];
#pragma unroll
  for (int i = 0; i < 2; i++)
#pragma unroll
    for (int j = 0; j < 4; j++) acc[i][j] = zero;

  for (int kb = 0; kb < K; kb += 64) {
    __syncthreads();
#pragma unroll
    for (int sec = 0; sec < 2; sec++) {
      {
        const int row = tid >> 2, seg = (tid & 3) * 8;
        gload16(&Ag[(size_t)(m0 + row) * K + kb + sec * 32 + seg],
                &As[sec * 2048 + (wid * 64) * 8]);
      }
#pragma unroll
      for (int it = 0; it < 2; it++) {
        const int idx = it * 256 + tid;
        const int row = idx >> 2, seg = (idx & 3) * 8;
        gload16(&Wg[(size_t)(n0 + row) * K + kb + sec * 32 + seg],
                &Bs[sec * 4096 + (it * 256 + wid * 64) * 8]);
      }
    }
    __syncthreads();
#pragma unroll
    for (int sec = 0; sec < 2; sec++) {
      short8 afr[2], bfr[4];
#pragma unroll
      for (int i = 0; i < 2; i++)
        afr[i] = *(const short8*)&As[sec * 2048 + (wm * 32 + i * 16 + lm) * 32 + quad * 8];
#pragma unroll
      for (int j = 0; j < 4; j++)
        bfr[j] = *(const short8*)&Bs[sec * 4096 + (wn * 64 + j * 16 + lm) * 32 + quad * 8];
#pragma unroll
      for (int i = 0; i < 2; i++)
#pragma unroll
        for (int j = 0; j < 4; j++)
          acc[i][j] = __builtin_amdgcn_mfma_f32_16x16x32_bf16(afr[i], bfr[j], acc[i][j], 0, 0, 0);
    }
  }
#pragma unroll
  for (int i = 0; i < 2; i++) {
    const int rbase = m0 + wm * 32 + i * 16 + quad * 4;
#pragma unroll
    for (int j = 0; j < 4; j++) {
      const int col = n0 + wn * 64 + j * 16 + lm;
      const float bval = bias[col];
#pragma unroll
      for (int r = 0; r < 4; r++)
        Cout[(size_t)(rbase + r) * DM + col] = acc[i][j][r] + bval;
    }
  }
}

// ---------------------------------------------------------------------------
// Pass A: per (h,c) Skv_c = K_g^T V with K gated+ELU'd during staging from
// bf16 raw k + bf16 gate + gate_accum. Sk_c = col sums of gated K.
// ---------------------------------------------------------------------------
__global__ __launch_bounds__(256, 2) void chunk_sum_mm(const short* __restrict__ Kb,
                                                       const short* __restrict__ Gb,
                                                       const float* __restrict__ ga,
                                                       const short* __restrict__ Vb,
                                                       float* __restrict__ Skv,
                                                       float* __restrict__ Sk) {
  constexpr int STR = 68;
  __shared__ __align__(16) float Ks2[64 * STR];
  __shared__ __align__(16) float Vs2[64 * STR];
  const int b = blockIdx.x;
  const int h = b >> 5, c = b & 31;
  const int tid = threadIdx.x;
  const int ty = tid >> 4, tx = tid & 15;
  const int d0 = ty * 4, m0 = tx * 4;
  const int t0 = c * CHUNK;
  const size_t cb = ((size_t)h * T_SEQ + t0) * DH;
#pragma unroll
  for (int p = 0; p < 4; p++) {
    int f = p * 256 + tid, row = f >> 4, seg = (f & 15) * 4;
    const int t = t0 + row;
    short4v kr = *(const short4v*)&Kb[cb + row * 64 + seg];
    short4v gr = *(const short4v*)&Gb[(size_t)t * DM + h * 64 + seg];
    short4v vr = *(const short4v*)&Vb[cb + row * 64 + seg];
    const float inv = 1.f / (ga[t] * (1.f / DM) + 1e-5f);
    f32x4 kgv, vv;
#pragma unroll
    for (int e = 0; e < 4; e++) {
      kgv[e] = gelu1(b2f(kr[e]), b2f(gr[e]), inv);
      vv[e] = b2f(vr[e]);
    }
    *(f32x4*)&Ks2[row * STR + seg] = kgv;
    *(f32x4*)&Vs2[row * STR + seg] = vv;
  }
  __syncthreads();
  float acc[4][4] = {};
#pragma unroll 4
  for (int s = 0; s < 64; s++) {
    f32x4 kf = *(const f32x4*)&Ks2[s * STR + d0];
    f32x4 vf = *(const f32x4*)&Vs2[s * STR + m0];
#pragma unroll
    for (int i = 0; i < 4; i++)
#pragma unroll
      for (int j = 0; j < 4; j++) acc[i][j] += kf[i] * vf[j];
  }
  float* outp = Skv + (size_t)b * 4096;
#pragma unroll
  for (int i = 0; i < 4; i++) {
    f32x4 o = {acc[i][0], acc[i][1], acc[i][2], acc[i][3]};
    *(f32x4*)&outp[(d0 + i) * 64 + m0] = o;
  }
  if (tid < 64) {
    float ss = 0.f;
#pragma unroll 4
    for (int s = 0; s < 64; s++) ss += Ks2[s * STR + tid];
    Sk[b * 64 + tid] = ss;
  }
}

// ---------------------------------------------------------------------------
// Pass B: exclusive prefix over chunks, one thread per (h,e) chain.
// ---------------------------------------------------------------------------
__global__ __launch_bounds__(256) void scan_excl(float* __restrict__ Skv,
                                                 float* __restrict__ Sk) {
  const int bid = blockIdx.x, tid = threadIdx.x;
  if (bid < 256) {
    const int id = bid * 256 + tid;
    const int h = id >> 12, e = id & 4095;
    float* base = Skv + (size_t)h * NCHUNK * 4096 + e;
    float v[NCHUNK];
#pragma unroll
    for (int c = 0; c < NCHUNK; c++) v[c] = base[(size_t)c * 4096];
    float run = 0.f;
#pragma unroll
    for (int c = 0; c < NCHUNK; c++) {
      float t = v[c];
      base[(size_t)c * 4096] = run;
      run += t;
    }
  } else {
    const int id = (bid - 256) * 256 + tid;
    const int h = id >> 6, e = id & 63;
    float* base = Sk + (size_t)h * NCHUNK * 64 + e;
    float v[NCHUNK];
#pragma unroll
    for (int c = 0; c < NCHUNK; c++) v[c] = base[c * 64];
    float run = 0.f;
#pragma unroll
    for (int c = 0; c < NCHUNK; c++) {
      float t = v[c];
      base[c * 64] = run;
      run += t;
    }
  }
}

// ---------------------------------------------------------------------------
// Pass C: per (h,c): accO = Q.P ; S = Q K^T (causal) ; accO += S.V ;
// den = q.Skp + rowsum(S). Gating+ELU applied to bf16 Q,K during staging.
// All in-loop operands from LDS; P/K share one region.
// ---------------------------------------------------------------------------
__global__ __launch_bounds__(256, 2) void attn_mm(const short* __restrict__ Qb,
                                                  const short* __restrict__ Kb,
                                                  const short* __restrict__ Gb,
                                                  const float* __restrict__ ga,
                                                  const short* __restrict__ Vb,
                                                  const float* __restrict__ Skv,
                                                  const float* __restrict__ Sk,
                                                  bf16* __restrict__ O) {
  constexpr int STR = 68;
  __shared__ __align__(16) float Qs[64 * STR];   // gated Q, later S
  __shared__ __align__(16) float Vs[64 * STR];
  __shared__ __align__(16) float KPs[64 * STR];  // P phase 1, gated K phase 2
  __shared__ float denp[64 * 16];
  __shared__ float skp[64];
  __shared__ float den[64];
  const int b = blockIdx.x;
  const int h = b >> 5, c = b & 31;
  const int tid = threadIdx.x;
  const int ty = tid >> 4, tx = tid & 15;
  const int r0 = ty * 4, c0 = tx * 4, m0 = tx * 4;
  const int t0 = c * CHUNK;
  const size_t cb = ((size_t)h * T_SEQ + t0) * DH;
  const float* Pg = Skv + (size_t)b * 4096;

  // K prefetch (raw + gate + inv) into registers; consumed in phase 2
  short4v kreg[4], greg[4];
  float ireg[4];
#pragma unroll
  for (int p = 0; p < 4; p++) {
    int f = p * 256 + tid, row = f >> 4, seg = (f & 15) * 4;
    kreg[p] = *(const short4v*)&Kb[cb + row * 64 + seg];
    greg[p] = *(const short4v*)&Gb[(size_t)(t0 + row) * DM + h * 64 + seg];
    ireg[p] = 1.f / (ga[t0 + row] * (1.f / DM) + 1e-5f);
  }
  // stage gated Q, V, P (coalesced)
#pragma unroll
  for (int p = 0; p < 4; p++) {
    int f = p * 256 + tid, row = f >> 4, seg = (f & 15) * 4;
    short4v qr = *(const short4v*)&Qb[cb + row * 64 + seg];
    short4v gq = *(const short4v*)&Gb[(size_t)(t0 + row) * DM + h * 64 + seg];
    short4v vr = *(const short4v*)&Vb[cb + row * 64 + seg];
    const float inv = 1.f / (ga[t0 + row] * (1.f / DM) + 1e-5f);
    f32x4 qgv, vv;
#pragma unroll
    for (int e = 0; e < 4; e++) {
      qgv[e] = gelu1(b2f(qr[e]), b2f(gq[e]), inv);
      vv[e] = b2f(vr[e]);
    }
    *(f32x4*)&Qs[row * STR + seg] = qgv;
    *(f32x4*)&Vs[row * STR + seg] = vv;
    *(f32x4*)&KPs[row * STR + seg] = *(const f32x4*)&Pg[row * 64 + seg];
  }
  if (tid < 64) skp[tid] = Sk[b * 64 + tid];
  __syncthreads();  // B1

  // den init: q . Sk_prefix + EPS_DEN
  if (tid < 64) {
    float s = 1e-5f;
#pragma unroll 4
    for (int d = 0; d < 64; d++) s += Qs[tid * STR + d] * skp[d];
    den[tid] = s;
  }

  // accO = Q . P
  float accO[4][4] = {};
#pragma unroll 2
  for (int d0 = 0; d0 < 64; d0 += 4) {
    f32x4 qf[4], pf[4];
#pragma unroll
    for (int i = 0; i < 4; i++) qf[i] = *(const f32x4*)&Qs[(r0 + i) * STR + d0];
#pragma unroll
    for (int dd = 0; dd < 4; dd++) pf[dd] = *(const f32x4*)&KPs[(d0 + dd) * STR + m0];
#pragma unroll
    for (int i = 0; i < 4; i++)
#pragma unroll
      for (int j = 0; j < 4; j++)
        accO[i][j] += qf[i][0] * pf[0][j] + qf[i][1] * pf[1][j] +
                      qf[i][2] * pf[2][j] + qf[i][3] * pf[3][j];
  }
  __syncthreads();  // B2: P reads done -> region becomes gated K
#pragma unroll
  for (int p = 0; p < 4; p++) {
    int f = p * 256 + tid, row = f >> 4, seg = (f & 15) * 4;
    f32x4 kgv;
#pragma unroll
    for (int e = 0; e < 4; e++) kgv[e] = gelu1(b2f(kreg[p][e]), b2f(greg[p][e]), ireg[p]);
    *(f32x4*)&KPs[row * STR + seg] = kgv;
  }
  __syncthreads();  // B3

  // S = Q K^T (row-dot, natural layout)
  float accS[4][4] = {};
#pragma unroll 2
  for (int d0 = 0; d0 < 64; d0 += 4) {
    f32x4 qf[4], kf[4];
#pragma unroll
    for (int i = 0; i < 4; i++) qf[i] = *(const f32x4*)&Qs[(r0 + i) * STR + d0];
#pragma unroll
    for (int j = 0; j < 4; j++) kf[j] = *(const f32x4*)&KPs[(c0 + j) * STR + d0];
#pragma unroll
    for (int i = 0; i < 4; i++)
#pragma unroll
      for (int j = 0; j < 4; j++)
        accS[i][j] += qf[i][0] * kf[j][0] + qf[i][1] * kf[j][1] +
                      qf[i][2] * kf[j][2] + qf[i][3] * kf[j][3];
  }
  // causal mask (inclusive) + row-sum partials
  float dp[4];
#pragma unroll
  for (int i = 0; i < 4; i++) {
    dp[i] = 0.f;
#pragma unroll
    for (int j = 0; j < 4; j++) {
      float v = (c0 + j) <= (r0 + i) ? accS[i][j] : 0.f;
      accS[i][j] = v;
      dp[i] += v;
    }
  }
  __syncthreads();  // B4: Qs reads complete -> overwrite with S
#pragma unroll
  for (int i = 0; i < 4; i++) {
    f32x4 sv = {accS[i][0], accS[i][1], accS[i][2], accS[i][3]};
    *(f32x4*)&Qs[(r0 + i) * STR + c0] = sv;
    denp[(r0 + i) * 16 + tx] = dp[i];
  }
  __syncthreads();  // B5
  if (tid < 64) {
    float s = den[tid];
#pragma unroll
    for (int t = 0; t < 16; t++) s += denp[tid * 16 + t];
    den[tid] = s;
  }

  // accO += S . V
#pragma unroll 2
  for (int c4 = 0; c4 < 64; c4 += 4) {
    f32x4 sf[4], vf[4];
#pragma unroll
    for (int i = 0; i < 4; i++) sf[i] = *(const f32x4*)&Qs[(r0 + i) * STR + c4];
#pragma unroll
    for (int cc = 0; cc < 4; cc++) vf[cc] = *(const f32x4*)&Vs[(c4 + cc) * STR + m0];
#pragma unroll
    for (int i = 0; i < 4; i++)
#pragma unroll
      for (int j = 0; j < 4; j++)
        accO[i][j] += sf[i][0] * vf[0][j] + sf[i][1] * vf[1][j] +
                      sf[i][2] * vf[2][j] + sf[i][3] * vf[3][j];
  }
  __syncthreads();  // B6: den final visible

#pragma unroll
  for (int i = 0; i < 4; i++) {
    const float inv = 1.f / den[r0 + i];
    short4v ov;
#pragma unroll
    for (int j = 0; j < 4; j++) ov[j] = f2b_bits(accO[i][j] * inv);
    *(short4v*)&O[(size_t)(t0 + r0 + i) * DM + h * 64 + m0] = ov;
  }
}

// ---------------------------------------------------------------------------
extern "C" void kernel_launch(void* const* d_in, const int* in_sizes, int n_in,
                              void* d_out, int out_size, void* d_ws, size_t ws_size,
                              hipStream_t stream) {
  (void)in_sizes; (void)n_in; (void)out_size; (void)ws_size;
  const float* x      = (const float*)d_in[0];
  const float* ln_g   = (const float*)d_in[1];
  const float* ln_b   = (const float*)d_in[2];
  const float* qkv_w  = (const float*)d_in[3];
  const float* qkv_b  = (const float*)d_in[4];
  const float* gate_w = (const float*)d_in[5];
  const float* gate_b = (const float*)d_in[6];
  const float* proj_w = (const float*)d_in[7];
  const float* proj_b = (const float*)d_in[8];
  float* out = (float*)d_out;

  char* ws = (char*)d_ws;
  size_t off = 0;
  auto alloc = [&](size_t bytes) {
    void* p = ws + off;
    off += (bytes + 255) & ~(size_t)255;
    return p;
  };
  bf16*  xn       = (bf16*)alloc((size_t)T_SEQ * DM * 2);
  bf16*  xbf      = (bf16*)alloc((size_t)T_SEQ * DM * 2);
  bf16*  wqkv     = (bf16*)alloc((size_t)3 * DM * DM * 2);
  bf16*  wgate    = (bf16*)alloc((size_t)DM * DM * 2);
  bf16*  wproj    = (bf16*)alloc((size_t)DM * DM * 2);
  short* Gb       = (short*)alloc((size_t)T_SEQ * DM * 2);
  float* gate_accum = (float*)alloc((size_t)T_SEQ * 4);
  short* Qb       = (short*)alloc((size_t)T_SEQ * DM * 2);
  short* Kb       = (short*)alloc((size_t)T_SEQ * DM * 2);
  short* Vb       = (short*)alloc((size_t)T_SEQ * DM * 2);
  bf16*  Obuf     = (bf16*)alloc((size_t)T_SEQ * DM * 2);
  float* Skv      = (float*)alloc((size_t)NH * NCHUNK * 4096 * 4);
  float* Sk       = (float*)alloc((size_t)NH * NCHUNK * 64 * 4);

  prep_kernel<<<T_SEQ + PREP_WBLOCKS, 256, 0, stream>>>(
      x, ln_g, ln_b, qkv_w, gate_w, proj_w, xn, xbf, wqkv, wgate, wproj, gate_accum);
  gemm_gateqkv<<<dim3(16, 32), 256, 0, stream>>>(xbf, xn, wgate, wqkv, gate_b, qkv_b,
                                                 Gb, gate_accum, Qb, Kb, Vb);
  chunk_sum_mm<<<NH * NCHUNK, 256, 0, stream>>>(Kb, Gb, gate_accum, Vb, Skv, Sk);
  scan_excl<<<260, 256, 0, stream>>>(Skv, Sk);
  attn_mm<<<NH * NCHUNK, 256, 0, stream>>>(Qb, Kb, Gb, gate_accum, Vb, Skv, Sk, Obuf);
  gemm_proj<<<dim3(32, 8), 256, 0, stream>>>(Obuf, wproj, proj_b, out);
}